// Round 2
// baseline (305.210 us; speedup 1.0000x reference)
//
#include <hip/hip_runtime.h>

typedef short short8 __attribute__((ext_vector_type(8)));
typedef float f32x4 __attribute__((ext_vector_type(4)));
typedef unsigned short u16;
typedef unsigned int u32;

#define NB 64
#define NH 256

__device__ __forceinline__ u16 f2bf(float f) {
  union { float f; u32 u; } x; x.f = f;
  u32 u = x.u;
  u32 r = (u + 0x7FFFu + ((u >> 16) & 1u)) >> 16;
  return (u16)r;
}

// ---------------- condition encoder + per-batch bond-layer1 cond term ----------------
__global__ void k_cond(const float* __restrict__ cnd, const float* __restrict__ W1,
                       const float* __restrict__ b1, const float* __restrict__ W2,
                       const float* __restrict__ b2, const float* __restrict__ bpW1,
                       const float* __restrict__ bpb1, float* __restrict__ cond_out,
                       float* __restrict__ ct_out) {
  __shared__ float h[NH], c2[NH];
  int b = blockIdx.x, t = threadIdx.x;
  float c0 = cnd[b * 2 + 0], c1 = cnd[b * 2 + 1];
  h[t] = fmaxf(c0 * W1[t] + c1 * W1[NH + t] + b1[t], 0.f);
  __syncthreads();
  float acc = b2[t];
  #pragma unroll 4
  for (int k = 0; k < NH; k++) acc += h[k] * W2[k * NH + t];
  cond_out[b * NH + t] = acc;
  c2[t] = acc;
  __syncthreads();
  float a2 = bpb1[t];
  #pragma unroll 4
  for (int k = 0; k < NH; k++) a2 += c2[k] * bpW1[(128 + k) * NH + t];
  ct_out[b * NH + t] = a2;
}

// ---------------- weight prep: W2T (bf16, [col][k]) and W3 padded-transposed ----------
__global__ void k_w3prep(const float* __restrict__ W2, const float* __restrict__ W3,
                         u16* __restrict__ W2T, u16* __restrict__ W3Tx) {
  int c = blockIdx.x, t = threadIdx.x;
  W2T[c * 256 + t] = f2bf(W2[t * 256 + c]);
  if (c < 16) {
    float v = (c < 4) ? W3[t * 4 + c] : 0.f;
    W3Tx[c * 256 + t] = f2bf(v);
  }
}

// ---------------- per-batch adj @ in  (in/out: [B,64,K]) -----------------------------
template <int K>
__global__ void k_adjmm(const float* __restrict__ adj, const float* __restrict__ in,
                        float* __restrict__ out) {
  __shared__ float adj_s[64 * 64];
  __shared__ float in_s[64 * 64];
  int b = blockIdx.y, ch = blockIdx.x, t = threadIdx.x;
  const float* A = adj + b * 4096;
  for (int e = t; e < 4096; e += 256) adj_s[e] = A[e];
  const float* I = in + b * 64 * K + ch * 64;
  for (int e = t; e < 4096; e += 256) { int j = e >> 6, c = e & 63; in_s[e] = I[j * K + c]; }
  __syncthreads();
  int c = t & 63, ig = t >> 6;
  float acc[16];
  #pragma unroll
  for (int m = 0; m < 16; m++) acc[m] = 0.f;
  for (int j = 0; j < 64; j++) {
    float v = in_s[j * 64 + c];
    #pragma unroll
    for (int m = 0; m < 16; m++) acc[m] += adj_s[(ig + m * 4) * 64 + j] * v;
  }
  float* O = out + b * 64 * K + ch * 64;
  #pragma unroll
  for (int m = 0; m < 16; m++) O[(ig + m * 4) * K + c] = acc[m];
}

// ---------------- generic rows x [K,256] linear (+relu) ------------------------------
template <int K, int MODE>  // MODE: 0 none, 1 relu
__global__ void k_lin256(const float* __restrict__ in, const float* __restrict__ W,
                         const float* __restrict__ bias, float* __restrict__ out) {
  __shared__ float in_s[16 * K];
  int t = threadIdx.x, r0 = blockIdx.x * 16;
  for (int e = t; e < 16 * K; e += 256) { int r = e / K, k = e % K; in_s[e] = in[(r0 + r) * K + k]; }
  __syncthreads();
  float acc[16];
  #pragma unroll
  for (int r = 0; r < 16; r++) acc[r] = 0.f;
  #pragma unroll 4
  for (int k = 0; k < K; k++) {
    float w = W[k * 256 + t];
    #pragma unroll
    for (int r = 0; r < 16; r++) acc[r] += in_s[r * K + k] * w;
  }
  float bv = bias[t];
  #pragma unroll
  for (int r = 0; r < 16; r++) {
    float v = acc[r] + bv;
    if (MODE == 1) v = fmaxf(v, 0.f);
    out[(r0 + r) * 256 + t] = v;
  }
}

// ---------------- mu / logvar heads ---------------------------------------------------
__global__ void k_mulv(const float* __restrict__ in, const float* __restrict__ Wmu,
                       const float* __restrict__ bmu, const float* __restrict__ Wlv,
                       const float* __restrict__ blv, float* __restrict__ mu_out,
                       float* __restrict__ lv_out) {
  __shared__ float in_s[16 * 256];
  __shared__ float part[4 * 16 * 64];
  int t = threadIdx.x, r0 = blockIdx.x * 16;
  for (int e = t; e < 4096; e += 256) in_s[e] = in[r0 * 256 + e];
  __syncthreads();
  int c = t & 63, g = t >> 6, sel = g >> 1, kh = g & 1;
  const float* W = sel ? Wlv : Wmu;
  float acc[16];
  #pragma unroll
  for (int r = 0; r < 16; r++) acc[r] = 0.f;
  #pragma unroll 4
  for (int k = kh * 128; k < kh * 128 + 128; k++) {
    float w = W[k * 64 + c];
    #pragma unroll
    for (int r = 0; r < 16; r++) acc[r] += in_s[r * 256 + k] * w;
  }
  #pragma unroll
  for (int r = 0; r < 16; r++) part[(g * 16 + r) * 64 + c] = acc[r];
  __syncthreads();
  if (t < 128) {
    int cc = t & 63, s2 = t >> 6;
    const float* bb = s2 ? blv : bmu;
    float* O = s2 ? lv_out : mu_out;
    float bv = bb[cc];
    #pragma unroll
    for (int r = 0; r < 16; r++)
      O[(r0 + r) * 64 + cc] =
          part[((s2 * 2) * 16 + r) * 64 + cc] + part[((s2 * 2 + 1) * 16 + r) * 64 + cc] + bv;
  }
}

// ---------------- decoder layer 1: [z | cond] @ W1 ------------------------------------
__global__ void k_dec1(const float* __restrict__ z, const float* __restrict__ cond,
                       const float* __restrict__ W1, const float* __restrict__ b1,
                       float* __restrict__ f1) {
  __shared__ float z_s[16 * 64];
  __shared__ float c_s[256];
  int t = threadIdx.x, r0 = blockIdx.x * 16, b = r0 >> 6;
  for (int e = t; e < 1024; e += 256) z_s[e] = z[r0 * 64 + e];
  c_s[t] = cond[b * 256 + t];
  __syncthreads();
  float acc[16];
  #pragma unroll
  for (int r = 0; r < 16; r++) acc[r] = 0.f;
  #pragma unroll 4
  for (int k = 0; k < 64; k++) {
    float w = W1[k * 256 + t];
    #pragma unroll
    for (int r = 0; r < 16; r++) acc[r] += z_s[r * 64 + k] * w;
  }
  float ctv = b1[t];
  #pragma unroll 4
  for (int k = 0; k < 256; k++) ctv += c_s[k] * W1[(64 + k) * 256 + t];
  #pragma unroll
  for (int r = 0; r < 16; r++) f1[(r0 + r) * 256 + t] = fmaxf(acc[r] + ctv, 0.f);
}

// ---------------- head: features, atom_features, valence, P, Q ------------------------
__global__ void k_head(const float* __restrict__ f2, const float* __restrict__ W3,
                       const float* __restrict__ b3, const float* __restrict__ reW1,
                       const float* __restrict__ reb1, const float* __restrict__ reW2,
                       const float* __restrict__ reb2, const float* __restrict__ bpW1,
                       float* __restrict__ af_out, float* __restrict__ val_out,
                       float* __restrict__ P, float* __restrict__ Q) {
  __shared__ float in_s[16 * 256];
  __shared__ float part[4 * 16 * 64];
  __shared__ float feat_s[16 * 64];
  __shared__ float rh_s[16 * 256];
  int t = threadIdx.x, r0 = blockIdx.x * 16;
  for (int e = t; e < 4096; e += 256) in_s[e] = f2[r0 * 256 + e];
  __syncthreads();
  int c = t & 63, g = t >> 6;
  {
    float acc[16];
    #pragma unroll
    for (int r = 0; r < 16; r++) acc[r] = 0.f;
    #pragma unroll 4
    for (int k = 64 * g; k < 64 * g + 64; k++) {
      float w = W3[k * 64 + c];
      #pragma unroll
      for (int r = 0; r < 16; r++) acc[r] += in_s[r * 256 + k] * w;
    }
    #pragma unroll
    for (int r = 0; r < 16; r++) part[(g * 16 + r) * 64 + c] = acc[r];
  }
  __syncthreads();
  if (t < 64) {
    float bv = b3[t];
    for (int r = 0; r < 16; r++) {
      float v = part[(0 * 16 + r) * 64 + t] + part[(1 * 16 + r) * 64 + t] +
                part[(2 * 16 + r) * 64 + t] + part[(3 * 16 + r) * 64 + t] + bv;
      v = 1.f / (1.f + expf(-v));
      feat_s[r * 64 + t] = v;
    }
  }
  __syncthreads();
  for (int e = t; e < 1024; e += 256) af_out[r0 * 64 + e] = feat_s[e] * 0.125f;
  // P,Q from af = feat*0.125
  {
    float accP[16], accQ[16];
    #pragma unroll
    for (int r = 0; r < 16; r++) { accP[r] = 0.f; accQ[r] = 0.f; }
    #pragma unroll 2
    for (int k = 0; k < 64; k++) {
      float wp = bpW1[k * 256 + t];
      float wq = bpW1[(64 + k) * 256 + t];
      #pragma unroll
      for (int r = 0; r < 16; r++) {
        float a = feat_s[r * 64 + k] * 0.125f;
        accP[r] += a * wp;
        accQ[r] += a * wq;
      }
    }
    #pragma unroll
    for (int r = 0; r < 16; r++) {
      P[(r0 + r) * 256 + t] = accP[r];
      Q[(r0 + r) * 256 + t] = accQ[r];
    }
  }
  // valence hidden
  {
    float accR[16];
    #pragma unroll
    for (int r = 0; r < 16; r++) accR[r] = 0.f;
    #pragma unroll 4
    for (int k = 0; k < 64; k++) {
      float w = reW1[k * 256 + t];
      #pragma unroll
      for (int r = 0; r < 16; r++) accR[r] += feat_s[r * 64 + k] * w;
    }
    float bv = reb1[t];
    #pragma unroll
    for (int r = 0; r < 16; r++) rh_s[r * 256 + t] = fmaxf(accR[r] + bv, 0.f);
  }
  __syncthreads();
  if (t < 64) {
    int r = t >> 2, cc = t & 3;
    float a = reb2[cc];
    for (int k = 0; k < 256; k++) a += rh_s[r * 256 + k] * reW2[k * 4 + cc];
    val_out[(r0 + r) * 4 + cc] = 4.f / (1.f + expf(-a));
  }
}

// ---------------- fused bond MLP: G1 build + MFMA GEMM + W3 + softmax ------------------
__global__ void k_bond(const float* __restrict__ P, const float* __restrict__ Q,
                       const float* __restrict__ ct, const u16* __restrict__ W2T,
                       const float* __restrict__ b2, const u16* __restrict__ W3Tx,
                       const float* __restrict__ b3, float* __restrict__ bp_out) {
  __shared__ u16 G[64 * 256];         // 32KB bf16, XOR-swizzled
  __shared__ float part[4 * 64 * 4];  // 4KB
  int i = blockIdx.x, b = blockIdx.y;
  int t = threadIdx.x;
  int lane = t & 63, w = t >> 6;
  int lr = lane & 15, lk = lane >> 4;

  // ---- build G1[j][k] = relu(P[b,i,k] + Q[b,j,k] + ct[b,k]) ----
  {
    int cp = t & 127;  // col pair -> bf16 cols 2cp,2cp+1
    int rh = t >> 7;
    const float* Pb = P + (b * 64 + i) * 256;
    const float* ctb = ct + b * 256;
    float2 p2 = *(const float2*)(Pb + 2 * cp);
    float2 cv = *(const float2*)(ctb + 2 * cp);
    float pc0 = p2.x + cv.x, pc1 = p2.y + cv.y;
    const float* Qb = Q + b * 64 * 256;
    #pragma unroll 4
    for (int r = rh * 32; r < rh * 32 + 32; r++) {
      float2 q2 = *(const float2*)(Qb + r * 256 + 2 * cp);
      float v0 = fmaxf(pc0 + q2.x, 0.f);
      float v1 = fmaxf(pc1 + q2.y, 0.f);
      u32 pk = (u32)f2bf(v0) | ((u32)f2bf(v1) << 16);
      int byt = (r * 512 + 4 * cp) ^ ((r & 7) << 4);
      *(u32*)((char*)G + byt) = pk;
    }
  }
  __syncthreads();

  // ---- GEMM1: g2 = relu(G1 @ W2 + b2); wave w owns cols [64w, 64w+64) ----
  f32x4 zero4 = {0.f, 0.f, 0.f, 0.f};
  f32x4 acc[4][4];
  #pragma unroll
  for (int mi = 0; mi < 4; mi++)
    #pragma unroll
    for (int ni = 0; ni < 4; ni++) acc[mi][ni] = zero4;

  for (int kk = 0; kk < 8; kk++) {
    short8 a[4], bw[4];
    #pragma unroll
    for (int mi = 0; mi < 4; mi++) {
      int row = mi * 16 + lr;
      int byt = (row * 512 + kk * 64 + lk * 16) ^ ((row & 7) << 4);
      a[mi] = *(const short8*)((const char*)G + byt);
    }
    #pragma unroll
    for (int ni = 0; ni < 4; ni++) {
      int col = w * 64 + ni * 16 + lr;
      bw[ni] = *(const short8*)(W2T + col * 256 + kk * 32 + lk * 8);
    }
    #pragma unroll
    for (int mi = 0; mi < 4; mi++)
      #pragma unroll
      for (int ni = 0; ni < 4; ni++)
        acc[mi][ni] = __builtin_amdgcn_mfma_f32_16x16x32_bf16(a[mi], bw[ni], acc[mi][ni], 0, 0, 0);
  }
  __syncthreads();  // all G1 reads complete before overwrite

  // ---- write g2 back as bf16 (same swizzled layout) ----
  #pragma unroll
  for (int ni = 0; ni < 4; ni++) {
    int col = w * 64 + ni * 16 + lr;
    float bv = b2[col];
    #pragma unroll
    for (int mi = 0; mi < 4; mi++) {
      #pragma unroll
      for (int rg = 0; rg < 4; rg++) {
        int row = mi * 16 + lk * 4 + rg;
        float v = fmaxf(acc[mi][ni][rg] + bv, 0.f);
        int byt = (row * 512 + col * 2) ^ ((row & 7) << 4);
        *(u16*)((char*)G + byt) = f2bf(v);
      }
    }
  }
  __syncthreads();

  // ---- GEMM2: logits = g2 @ W3 (padded to 16 cols); wave w does K-slice [64w,64w+64) --
  f32x4 acc2[4];
  #pragma unroll
  for (int mi = 0; mi < 4; mi++) acc2[mi] = zero4;
  #pragma unroll
  for (int kk = 0; kk < 2; kk++) {
    short8 bw2 = *(const short8*)(W3Tx + lr * 256 + w * 64 + kk * 32 + lk * 8);
    #pragma unroll
    for (int mi = 0; mi < 4; mi++) {
      int row = mi * 16 + lr;
      int kbyte = (w * 64 + kk * 32 + lk * 8) * 2;
      int byt = (row * 512 + kbyte) ^ ((row & 7) << 4);
      short8 a = *(const short8*)((const char*)G + byt);
      acc2[mi] = __builtin_amdgcn_mfma_f32_16x16x32_bf16(a, bw2, acc2[mi], 0, 0, 0);
    }
  }
  if (lr < 4) {
    #pragma unroll
    for (int mi = 0; mi < 4; mi++)
      #pragma unroll
      for (int rg = 0; rg < 4; rg++) {
        int row = mi * 16 + lk * 4 + rg;
        part[(w * 64 + row) * 4 + lr] = acc2[mi][rg];
      }
  }
  __syncthreads();

  if (t < 64) {
    int r = t;
    float l[4];
    #pragma unroll
    for (int c = 0; c < 4; c++)
      l[c] = part[(0 * 64 + r) * 4 + c] + part[(1 * 64 + r) * 4 + c] +
             part[(2 * 64 + r) * 4 + c] + part[(3 * 64 + r) * 4 + c] + b3[c];
    float m = fmaxf(fmaxf(l[0], l[1]), fmaxf(l[2], l[3]));
    float e0 = expf(l[0] - m), e1 = expf(l[1] - m), e2 = expf(l[2] - m), e3 = expf(l[3] - m);
    float inv = 1.f / (e0 + e1 + e2 + e3);
    float4 o;
    o.x = e0 * inv; o.y = e1 * inv; o.z = e2 * inv; o.w = e3 * inv;
    *(float4*)(bp_out + ((b * 64 + i) * 64 + r) * 4) = o;
  }
}

extern "C" void kernel_launch(void* const* d_in, const int* in_sizes, int n_in,
                              void* d_out, int out_size, void* d_ws, size_t ws_size,
                              hipStream_t stream) {
  const float* x    = (const float*)d_in[0];
  const float* adj  = (const float*)d_in[1];
  const float* cnd  = (const float*)d_in[2];
  const float* gc1W = (const float*)d_in[3];
  const float* gc1b = (const float*)d_in[4];
  const float* gc2W = (const float*)d_in[5];
  const float* gc2b = (const float*)d_in[6];
  const float* gmuW = (const float*)d_in[7];
  const float* gmub = (const float*)d_in[8];
  const float* glvW = (const float*)d_in[9];
  const float* glvb = (const float*)d_in[10];
  const float* ceW1 = (const float*)d_in[11];
  const float* ceb1 = (const float*)d_in[12];
  const float* ceW2 = (const float*)d_in[13];
  const float* ceb2 = (const float*)d_in[14];
  const float* dW1  = (const float*)d_in[15];
  const float* db1  = (const float*)d_in[16];
  const float* dW2  = (const float*)d_in[17];
  const float* db2  = (const float*)d_in[18];
  const float* dW3  = (const float*)d_in[19];
  const float* db3  = (const float*)d_in[20];
  // d_in[21..24] (at_*) are mathematically dead: mean(softmax) == 1/8 exactly
  const float* bpW1 = (const float*)d_in[25];
  const float* bpb1 = (const float*)d_in[26];
  const float* bpW2 = (const float*)d_in[27];
  const float* bpb2 = (const float*)d_in[28];
  const float* bpW3 = (const float*)d_in[29];
  const float* bpb3 = (const float*)d_in[30];
  const float* reW1 = (const float*)d_in[31];
  const float* reb1 = (const float*)d_in[32];
  const float* reW2 = (const float*)d_in[33];
  const float* reb2 = (const float*)d_in[34];

  float* out = (float*)d_out;
  float* af_out  = out;            // [64,64,64]
  float* bp_out  = out + 262144;   // [64,64,64,4]
  float* val_out = out + 1310720;  // [64,64,4]
  float* mu_out  = out + 1327104;  // [64,64,64]
  float* lv_out  = out + 1589248;  // [64,64,64]

  float* ws   = (float*)d_ws;
  float* cond = ws;                 // 16384
  float* ct   = ws + 16384;         // 16384
  float* ax   = ws + 32768;         // 262144
  float* buf1 = ws + 294912;        // 1048576
  float* buf2 = buf1 + 1048576;     // 1048576
  float* buf3 = buf2 + 1048576;     // 1048576
  u16* W2T    = (u16*)(buf3 + 1048576);  // 65536 u16
  u16* W3Tx   = W2T + 65536;             // 4096 u16

  k_cond<<<64, 256, 0, stream>>>(cnd, ceW1, ceb1, ceW2, ceb2, bpW1, bpb1, cond, ct);
  k_w3prep<<<256, 256, 0, stream>>>(bpW2, bpW3, W2T, W3Tx);
  k_adjmm<64><<<dim3(1, 64), 256, 0, stream>>>(adj, x, ax);
  k_lin256<64, 1><<<256, 256, 0, stream>>>(ax, gc1W, gc1b, buf1);        // h1
  k_adjmm<256><<<dim3(4, 64), 256, 0, stream>>>(adj, buf1, buf2);        // ah1
  k_lin256<256, 1><<<256, 256, 0, stream>>>(buf2, gc2W, gc2b, buf3);     // h2
  k_adjmm<256><<<dim3(4, 64), 256, 0, stream>>>(adj, buf3, buf1);        // ah2
  k_mulv<<<256, 256, 0, stream>>>(buf1, gmuW, gmub, glvW, glvb, mu_out, lv_out);
  k_dec1<<<256, 256, 0, stream>>>(mu_out, cond, dW1, db1, buf2);         // f1
  k_lin256<256, 1><<<256, 256, 0, stream>>>(buf2, dW2, db2, buf3);       // f2
  k_head<<<256, 256, 0, stream>>>(buf3, dW3, db3, reW1, reb1, reW2, reb2, bpW1,
                                  af_out, val_out, buf1, buf2);          // P=buf1, Q=buf2
  k_bond<<<dim3(64, 64), 256, 0, stream>>>(buf1, buf2, ct, W2T, bpb2, W3Tx, bpb3, bp_out);
}

// Round 4
// 253.930 us; speedup vs baseline: 1.2019x; 1.2019x over previous
//
#include <hip/hip_runtime.h>

typedef short short8 __attribute__((ext_vector_type(8)));
typedef float f32x4 __attribute__((ext_vector_type(4)));
typedef unsigned short u16;
typedef unsigned int u32;

#define NH 256

__device__ __forceinline__ u16 f2bf(float f) {
  union { float f; u32 u; } x; x.f = f;
  u32 u = x.u;
  u32 r = (u + 0x7FFFu + ((u >> 16) & 1u)) >> 16;
  return (u16)r;
}

__device__ __forceinline__ u32 cvtpk(float lo, float hi) {
  u32 r;
  asm("v_cvt_pk_bf16_f32 %0, %1, %2" : "=v"(r) : "v"(lo), "v"(hi));
  return r;
}

// ---- fused: condition encoder (+ct) [blocks 0..63] and W2T/W3Tx prep [blocks 64..319] --
__global__ void k_prep(const float* __restrict__ cnd, const float* __restrict__ W1,
                       const float* __restrict__ b1, const float* __restrict__ W2,
                       const float* __restrict__ b2, const float* __restrict__ bpW1,
                       const float* __restrict__ bpb1, const float* __restrict__ bW2,
                       const float* __restrict__ bW3, float* __restrict__ cond_out,
                       float* __restrict__ ct_out, u16* __restrict__ W2T,
                       u16* __restrict__ W3Tx) {
  __shared__ float h[NH], c2[NH];
  int bid = blockIdx.x, t = threadIdx.x;
  if (bid >= 64) {
    int c = bid - 64;
    W2T[c * 256 + t] = f2bf(bW2[t * 256 + c]);
    if (c < 16) {
      float v = (c < 4) ? bW3[t * 4 + c] : 0.f;
      W3Tx[c * 256 + t] = f2bf(v);
    }
    return;
  }
  int b = bid;
  float c0 = cnd[b * 2 + 0], c1 = cnd[b * 2 + 1];
  h[t] = fmaxf(c0 * W1[t] + c1 * W1[NH + t] + b1[t], 0.f);
  __syncthreads();
  float acc = b2[t];
  #pragma unroll 4
  for (int k = 0; k < NH; k++) acc += h[k] * W2[k * NH + t];
  cond_out[b * NH + t] = acc;
  c2[t] = acc;
  __syncthreads();
  float a2 = bpb1[t];
  #pragma unroll 4
  for (int k = 0; k < NH; k++) a2 += c2[k] * bpW1[(128 + k) * NH + t];
  ct_out[b * NH + t] = a2;
}

// ---------------- per-batch adj @ in  (in/out: [B,64,K]); 512 threads ----------------
template <int K>
__global__ void k_adjmm(const float* __restrict__ adj, const float* __restrict__ in,
                        float* __restrict__ out) {
  __shared__ float adj_s[64 * 64];
  __shared__ float in_s[64 * 64];
  int b = blockIdx.y, ch = blockIdx.x, t = threadIdx.x;
  const float* A = adj + b * 4096;
  for (int e = t; e < 4096; e += 512) adj_s[e] = A[e];
  const float* I = in + b * 64 * K + ch * 64;
  for (int e = t; e < 4096; e += 512) { int j = e >> 6, c = e & 63; in_s[e] = I[j * K + c]; }
  __syncthreads();
  int c = t & 63, ig = t >> 6;  // ig 0..7
  float acc[8];
  #pragma unroll
  for (int m = 0; m < 8; m++) acc[m] = 0.f;
  for (int j = 0; j < 64; j++) {
    float v = in_s[j * 64 + c];
    #pragma unroll
    for (int m = 0; m < 8; m++) acc[m] += adj_s[(ig + m * 8) * 64 + j] * v;
  }
  float* O = out + b * 64 * K + ch * 64;
  #pragma unroll
  for (int m = 0; m < 8; m++) O[(ig + m * 8) * K + c] = acc[m];
}

// ---------------- rows x [K,256] linear (+relu); 512 threads, K-split 2 --------------
template <int K, int MODE>
__global__ void k_lin256(const float* __restrict__ in, const float* __restrict__ W,
                         const float* __restrict__ bias, float* __restrict__ out) {
  __shared__ float in_s[16 * K];
  __shared__ float part[16 * 256];
  int t = threadIdx.x, r0 = blockIdx.x * 16;
  for (int e = t; e < 16 * K; e += 512) { int r = e / K, k = e % K; in_s[e] = in[(r0 + r) * K + k]; }
  __syncthreads();
  int col = t & 255, g = t >> 8;
  constexpr int KH = K / 2;
  float acc[16];
  #pragma unroll
  for (int r = 0; r < 16; r++) acc[r] = 0.f;
  #pragma unroll 4
  for (int k = g * KH; k < g * KH + KH; k++) {
    float w = W[k * 256 + col];
    #pragma unroll
    for (int r = 0; r < 16; r++) acc[r] += in_s[r * K + k] * w;
  }
  if (g == 1) {
    #pragma unroll
    for (int r = 0; r < 16; r++) part[r * 256 + col] = acc[r];
  }
  __syncthreads();
  if (g == 0) {
    float bv = bias[col];
    #pragma unroll
    for (int r = 0; r < 16; r++) {
      float v = acc[r] + part[r * 256 + col] + bv;
      if (MODE == 1) v = fmaxf(v, 0.f);
      out[(r0 + r) * 256 + col] = v;
    }
  }
}

// ---------------- mu / logvar heads; 512 threads, K-split 4 ---------------------------
__global__ void k_mulv(const float* __restrict__ in, const float* __restrict__ Wmu,
                       const float* __restrict__ bmu, const float* __restrict__ Wlv,
                       const float* __restrict__ blv, float* __restrict__ mu_out,
                       float* __restrict__ lv_out) {
  __shared__ float in_s[16 * 256];
  __shared__ float part[8 * 16 * 64];
  int t = threadIdx.x, r0 = blockIdx.x * 16;
  for (int e = t; e < 4096; e += 512) in_s[e] = in[r0 * 256 + e];
  __syncthreads();
  int c = t & 63, g = t >> 6;  // g 0..7
  int sel = g >> 2, kq = g & 3;
  const float* W = sel ? Wlv : Wmu;
  float acc[16];
  #pragma unroll
  for (int r = 0; r < 16; r++) acc[r] = 0.f;
  #pragma unroll 4
  for (int k = kq * 64; k < kq * 64 + 64; k++) {
    float w = W[k * 64 + c];
    #pragma unroll
    for (int r = 0; r < 16; r++) acc[r] += in_s[r * 256 + k] * w;
  }
  #pragma unroll
  for (int r = 0; r < 16; r++) part[(g * 16 + r) * 64 + c] = acc[r];
  __syncthreads();
  if (t < 128) {
    int cc = t & 63, s2 = t >> 6;
    const float* bb = s2 ? blv : bmu;
    float* O = s2 ? lv_out : mu_out;
    float bv = bb[cc];
    #pragma unroll
    for (int r = 0; r < 16; r++) {
      float v = bv;
      #pragma unroll
      for (int q = 0; q < 4; q++) v += part[((s2 * 4 + q) * 16 + r) * 64 + cc];
      O[(r0 + r) * 64 + cc] = v;
    }
  }
}

// ---------------- decoder layer 1; 512 threads ---------------------------------------
__global__ void k_dec1(const float* __restrict__ z, const float* __restrict__ cond,
                       const float* __restrict__ W1, const float* __restrict__ b1,
                       float* __restrict__ f1) {
  __shared__ float z_s[16 * 64];
  __shared__ float ctv_s[256];
  int t = threadIdx.x, r0 = blockIdx.x * 16, b = r0 >> 6;
  for (int e = t; e < 1024; e += 512) z_s[e] = z[r0 * 64 + e];
  int col = t & 255, g = t >> 8;
  if (g == 1) {
    float ctv = b1[col];
    #pragma unroll 4
    for (int k = 0; k < 256; k++) ctv += cond[b * 256 + k] * W1[(64 + k) * 256 + col];
    ctv_s[col] = ctv;
  }
  __syncthreads();
  if (g == 0) {
    float acc[16];
    #pragma unroll
    for (int r = 0; r < 16; r++) acc[r] = 0.f;
    #pragma unroll 4
    for (int k = 0; k < 64; k++) {
      float w = W1[k * 256 + col];
      #pragma unroll
      for (int r = 0; r < 16; r++) acc[r] += z_s[r * 64 + k] * w;
    }
    float cv = ctv_s[col];
    #pragma unroll
    for (int r = 0; r < 16; r++) f1[(r0 + r) * 256 + col] = fmaxf(acc[r] + cv, 0.f);
  }
}

// ---------------- head: features, af, valence, P(+ct), Q; 512 threads -----------------
__global__ void k_head(const float* __restrict__ f2, const float* __restrict__ W3,
                       const float* __restrict__ b3, const float* __restrict__ reW1,
                       const float* __restrict__ reb1, const float* __restrict__ reW2,
                       const float* __restrict__ reb2, const float* __restrict__ bpW1,
                       const float* __restrict__ ct, float* __restrict__ af_out,
                       float* __restrict__ val_out, float* __restrict__ P,
                       float* __restrict__ Q) {
  __shared__ float in_s[16 * 256];
  __shared__ float part[8 * 16 * 64];
  __shared__ float feat_s[16 * 64];
  __shared__ float rh_s[16 * 260];
  int t = threadIdx.x, r0 = blockIdx.x * 16, b = r0 >> 6;
  for (int e = t; e < 4096; e += 512) in_s[e] = f2[r0 * 256 + e];
  __syncthreads();
  {
    int c = t & 63, g = t >> 6;  // g 0..7
    float acc[16];
    #pragma unroll
    for (int r = 0; r < 16; r++) acc[r] = 0.f;
    #pragma unroll 4
    for (int k = g * 32; k < g * 32 + 32; k++) {
      float w = W3[k * 64 + c];
      #pragma unroll
      for (int r = 0; r < 16; r++) acc[r] += in_s[r * 256 + k] * w;
    }
    #pragma unroll
    for (int r = 0; r < 16; r++) part[(g * 16 + r) * 64 + c] = acc[r];
  }
  __syncthreads();
  if (t < 64) {
    float bv = b3[t];
    for (int r = 0; r < 16; r++) {
      float v = bv;
      #pragma unroll
      for (int q = 0; q < 8; q++) v += part[(q * 16 + r) * 64 + t];
      feat_s[r * 64 + t] = 1.f / (1.f + expf(-v));
    }
  }
  __syncthreads();
  for (int e = t; e < 1024; e += 512) af_out[r0 * 64 + e] = feat_s[e] * 0.125f;
  {
    int col = t & 255, gh = t >> 8;  // gh0 -> P, gh1 -> Q
    const float* Wsel = bpW1 + gh * 64 * 256;
    float acc[16];
    #pragma unroll
    for (int r = 0; r < 16; r++) acc[r] = 0.f;
    #pragma unroll 2
    for (int k = 0; k < 64; k++) {
      float w = Wsel[k * 256 + col] * 0.125f;
      #pragma unroll
      for (int r = 0; r < 16; r++) acc[r] += feat_s[r * 64 + k] * w;
    }
    if (gh == 0) {
      float cv = ct[b * 256 + col];
      #pragma unroll
      for (int r = 0; r < 16; r++) P[(r0 + r) * 256 + col] = acc[r] + cv;
    } else {
      #pragma unroll
      for (int r = 0; r < 16; r++) Q[(r0 + r) * 256 + col] = acc[r];
    }
  }
  {
    int col = t & 255, gh = t >> 8;  // rows gh*8..gh*8+8
    float accR[8];
    #pragma unroll
    for (int r = 0; r < 8; r++) accR[r] = 0.f;
    #pragma unroll 4
    for (int k = 0; k < 64; k++) {
      float w = reW1[k * 256 + col];
      #pragma unroll
      for (int r = 0; r < 8; r++) accR[r] += feat_s[(gh * 8 + r) * 64 + k] * w;
    }
    float bv = reb1[col];
    #pragma unroll
    for (int r = 0; r < 8; r++) rh_s[(gh * 8 + r) * 260 + col] = fmaxf(accR[r] + bv, 0.f);
  }
  __syncthreads();
  // valence: 256 threads = 16 rows x 4 cols x 4 K-quarters; shuffle-reduce the quarters
  if (t < 256) {
    int r = t >> 4;          // 0..15
    int cc = (t >> 2) & 3;   // 0..3
    int kq = t & 3;          // 0..3
    float a = 0.f;
    #pragma unroll 4
    for (int k = kq * 64; k < kq * 64 + 64; k++) a += rh_s[r * 260 + k] * reW2[k * 4 + cc];
    a += __shfl_xor(a, 1);
    a += __shfl_xor(a, 2);
    if (kq == 0) val_out[(r0 + r) * 4 + cc] = 4.f / (1.f + expf(-(a + reb2[cc])));
  }
}

// ---------------- fused bond MLP v2: swapped-operand MFMA, b64 writeback ---------------
__global__ void k_bond(const float* __restrict__ P, const float* __restrict__ Q,
                       const u16* __restrict__ W2T, const float* __restrict__ b2,
                       const u16* __restrict__ W3Tx, const float* __restrict__ b3,
                       float* __restrict__ bp_out) {
  __shared__ u16 G[64 * 256];         // 32KB bf16, XOR-swizzled rows
  __shared__ float part[4 * 64 * 4];  // 4KB
  int i = blockIdx.x, b = blockIdx.y;
  int t = threadIdx.x;
  int lane = t & 63, w = t >> 6;
  int lr = lane & 15, lk = lane >> 4;

  // ---- build G1[j][k] = relu(P'[b,i,k] + Q[b,j,k])  (ct pre-folded into P') ----
  {
    int colg = t & 63, rq = t >> 6;
    float4 pv = *(const float4*)(P + (b * 64 + i) * 256 + colg * 4);
    const float* Qb = Q + b * 64 * 256;
    #pragma unroll 4
    for (int r = rq * 16; r < rq * 16 + 16; r++) {
      float4 q4 = *(const float4*)(Qb + r * 256 + colg * 4);
      float v0 = fmaxf(pv.x + q4.x, 0.f), v1 = fmaxf(pv.y + q4.y, 0.f);
      float v2 = fmaxf(pv.z + q4.z, 0.f), v3 = fmaxf(pv.w + q4.w, 0.f);
      uint2 pk;
      pk.x = cvtpk(v0, v1);
      pk.y = cvtpk(v2, v3);
      int byt = (r * 512 + colg * 8) ^ ((r & 7) << 4);
      *(uint2*)((char*)G + byt) = pk;
    }
  }
  __syncthreads();

  // ---- GEMM1 (swapped): acc[ni][mi] lane holds 4 consecutive OUT-COLS of one row ----
  f32x4 zero4 = {0.f, 0.f, 0.f, 0.f};
  f32x4 acc[4][4];
  #pragma unroll
  for (int ni = 0; ni < 4; ni++)
    #pragma unroll
    for (int mi = 0; mi < 4; mi++) acc[ni][mi] = zero4;

  for (int kk = 0; kk < 8; kk++) {
    short8 a[4], bw[4];
    #pragma unroll
    for (int mi = 0; mi < 4; mi++) {
      int row = mi * 16 + lr;
      int byt = (row * 512 + kk * 64 + lk * 16) ^ ((row & 7) << 4);
      a[mi] = *(const short8*)((const char*)G + byt);
    }
    #pragma unroll
    for (int ni = 0; ni < 4; ni++) {
      int col = w * 64 + ni * 16 + lr;
      bw[ni] = *(const short8*)(W2T + col * 256 + kk * 32 + lk * 8);
    }
    #pragma unroll
    for (int ni = 0; ni < 4; ni++)
      #pragma unroll
      for (int mi = 0; mi < 4; mi++)
        acc[ni][mi] = __builtin_amdgcn_mfma_f32_16x16x32_bf16(bw[ni], a[mi], acc[ni][mi], 0, 0, 0);
  }
  __syncthreads();  // all G1 reads complete before overwrite

  // ---- writeback g2 (bias+relu) as bf16, row-major swizzled, b64 stores ----
  #pragma unroll
  for (int ni = 0; ni < 4; ni++) {
    int col0 = w * 64 + ni * 16 + lk * 4;
    float4 bb = *(const float4*)(b2 + col0);
    #pragma unroll
    for (int mi = 0; mi < 4; mi++) {
      int grow = mi * 16 + lr;
      float v0 = fmaxf(acc[ni][mi][0] + bb.x, 0.f);
      float v1 = fmaxf(acc[ni][mi][1] + bb.y, 0.f);
      float v2 = fmaxf(acc[ni][mi][2] + bb.z, 0.f);
      float v3 = fmaxf(acc[ni][mi][3] + bb.w, 0.f);
      uint2 pk;
      pk.x = cvtpk(v0, v1);
      pk.y = cvtpk(v2, v3);
      int byt = (grow * 512 + col0 * 2) ^ ((grow & 7) << 4);
      *(uint2*)((char*)G + byt) = pk;
    }
  }
  __syncthreads();

  // ---- GEMM2: logits = g2 @ W3 (padded 16 cols); wave w K-slice [64w,64w+64) ----
  f32x4 acc2[4];
  #pragma unroll
  for (int mi = 0; mi < 4; mi++) acc2[mi] = zero4;
  #pragma unroll
  for (int kk = 0; kk < 2; kk++) {
    short8 bw2 = *(const short8*)(W3Tx + lr * 256 + w * 64 + kk * 32 + lk * 8);
    #pragma unroll
    for (int mi = 0; mi < 4; mi++) {
      int row = mi * 16 + lr;
      int kbyte = (w * 64 + kk * 32 + lk * 8) * 2;
      int byt = (row * 512 + kbyte) ^ ((row & 7) << 4);
      short8 a = *(const short8*)((const char*)G + byt);
      acc2[mi] = __builtin_amdgcn_mfma_f32_16x16x32_bf16(a, bw2, acc2[mi], 0, 0, 0);
    }
  }
  if (lr < 4) {
    #pragma unroll
    for (int mi = 0; mi < 4; mi++)
      #pragma unroll
      for (int rg = 0; rg < 4; rg++) {
        int row = mi * 16 + lk * 4 + rg;
        part[(w * 64 + row) * 4 + lr] = acc2[mi][rg];
      }
  }
  __syncthreads();

  if (t < 64) {
    int r = t;
    float l[4];
    #pragma unroll
    for (int c = 0; c < 4; c++)
      l[c] = part[(0 * 64 + r) * 4 + c] + part[(1 * 64 + r) * 4 + c] +
             part[(2 * 64 + r) * 4 + c] + part[(3 * 64 + r) * 4 + c] + b3[c];
    float m = fmaxf(fmaxf(l[0], l[1]), fmaxf(l[2], l[3]));
    float e0 = expf(l[0] - m), e1 = expf(l[1] - m), e2 = expf(l[2] - m), e3 = expf(l[3] - m);
    float inv = 1.f / (e0 + e1 + e2 + e3);
    float4 o;
    o.x = e0 * inv; o.y = e1 * inv; o.z = e2 * inv; o.w = e3 * inv;
    *(float4*)(bp_out + ((b * 64 + i) * 64 + r) * 4) = o;
  }
}

extern "C" void kernel_launch(void* const* d_in, const int* in_sizes, int n_in,
                              void* d_out, int out_size, void* d_ws, size_t ws_size,
                              hipStream_t stream) {
  const float* x    = (const float*)d_in[0];
  const float* adj  = (const float*)d_in[1];
  const float* cnd  = (const float*)d_in[2];
  const float* gc1W = (const float*)d_in[3];
  const float* gc1b = (const float*)d_in[4];
  const float* gc2W = (const float*)d_in[5];
  const float* gc2b = (const float*)d_in[6];
  const float* gmuW = (const float*)d_in[7];
  const float* gmub = (const float*)d_in[8];
  const float* glvW = (const float*)d_in[9];
  const float* glvb = (const float*)d_in[10];
  const float* ceW1 = (const float*)d_in[11];
  const float* ceb1 = (const float*)d_in[12];
  const float* ceW2 = (const float*)d_in[13];
  const float* ceb2 = (const float*)d_in[14];
  const float* dW1  = (const float*)d_in[15];
  const float* db1  = (const float*)d_in[16];
  const float* dW2  = (const float*)d_in[17];
  const float* db2  = (const float*)d_in[18];
  const float* dW3  = (const float*)d_in[19];
  const float* db3  = (const float*)d_in[20];
  // d_in[21..24] (at_*) are dead: mean(softmax) == 1/8 exactly
  const float* bpW1 = (const float*)d_in[25];
  const float* bpb1 = (const float*)d_in[26];
  const float* bpW2 = (const float*)d_in[27];
  const float* bpb2 = (const float*)d_in[28];
  const float* bpW3 = (const float*)d_in[29];
  const float* bpb3 = (const float*)d_in[30];
  const float* reW1 = (const float*)d_in[31];
  const float* reb1 = (const float*)d_in[32];
  const float* reW2 = (const float*)d_in[33];
  const float* reb2 = (const float*)d_in[34];

  float* out = (float*)d_out;
  float* af_out  = out;            // [64,64,64]
  float* bp_out  = out + 262144;   // [64,64,64,4]
  float* val_out = out + 1310720;  // [64,64,4]
  float* mu_out  = out + 1327104;  // [64,64,64]
  float* lv_out  = out + 1589248;  // [64,64,64]

  float* ws   = (float*)d_ws;
  float* cond = ws;                 // 16384
  float* ct   = ws + 16384;         // 16384
  float* ax   = ws + 32768;         // 262144
  float* buf1 = ws + 294912;        // 1048576
  float* buf2 = buf1 + 1048576;     // 1048576
  float* buf3 = buf2 + 1048576;     // 1048576
  u16* W2T    = (u16*)(buf3 + 1048576);  // 65536 u16
  u16* W3Tx   = W2T + 65536;             // 4096 u16

  k_prep<<<320, 256, 0, stream>>>(cnd, ceW1, ceb1, ceW2, ceb2, bpW1, bpb1, bpW2, bpW3,
                                  cond, ct, W2T, W3Tx);
  k_adjmm<64><<<dim3(1, 64), 512, 0, stream>>>(adj, x, ax);
  k_lin256<64, 1><<<256, 512, 0, stream>>>(ax, gc1W, gc1b, buf1);        // h1
  k_adjmm<256><<<dim3(4, 64), 512, 0, stream>>>(adj, buf1, buf2);        // ah1
  k_lin256<256, 1><<<256, 512, 0, stream>>>(buf2, gc2W, gc2b, buf3);     // h2
  k_adjmm<256><<<dim3(4, 64), 512, 0, stream>>>(adj, buf3, buf1);        // ah2
  k_mulv<<<256, 512, 0, stream>>>(buf1, gmuW, gmub, glvW, glvb, mu_out, lv_out);
  k_dec1<<<256, 512, 0, stream>>>(mu_out, cond, dW1, db1, buf2);         // f1
  k_lin256<256, 1><<<256, 512, 0, stream>>>(buf2, dW2, db2, buf3);       // f2
  k_head<<<256, 512, 0, stream>>>(buf3, dW3, db3, reW1, reb1, reW2, reb2, bpW1, ct,
                                  af_out, val_out, buf1, buf2);          // P'=buf1, Q=buf2
  k_bond<<<dim3(64, 64), 256, 0, stream>>>(buf1, buf2, W2T, bpb2, W3Tx, bpb3, bp_out);
}

// Round 6
// 228.050 us; speedup vs baseline: 1.3383x; 1.1135x over previous
//
#include <hip/hip_runtime.h>

typedef short short8 __attribute__((ext_vector_type(8)));
typedef float f32x4 __attribute__((ext_vector_type(4)));
typedef unsigned short u16;
typedef unsigned int u32;

__device__ __forceinline__ u16 f2bf(float f) {
  union { float f; u32 u; } x; x.f = f;
  u32 u = x.u;
  u32 r = (u + 0x7FFFu + ((u >> 16) & 1u)) >> 16;
  return (u16)r;
}

__device__ __forceinline__ u32 cvtpk(float lo, float hi) {
  u32 r;
  asm("v_cvt_pk_bf16_f32 %0, %1, %2" : "=v"(r) : "v"(lo), "v"(hi));
  return r;
}

// ---- WB bf16-region offsets (u16 units) — decoder + bond weights only ----
#define OW2T   0        // bond W2^T      [256][256]
#define OW3TX  65536    // bond W3 padT   [16][256]
#define ODW1A  69632    // dW1[0:64]^T    [256][64]
#define ODW2   86016    // dW2^T          [256][256]
#define ODW3   151552   // dW3^T          [64][256]
#define OBPA   167936   // bpW1[0:64]^T   [256][64]  x0.125
#define OBPB   184320   // bpW1[64:128]^T [256][64]  x0.125
#define OREW1  200704   // reW1^T         [256][64]
#define OREW2  217088   // reW2 padT      [16][256]
// total 221184 u16

// =============== k_prep: ctf/ctv (blocks 0..63) + weight transposes (64..117) =========
__global__ void k_prep(const float* __restrict__ cnd, const float* __restrict__ ceW1,
                       const float* __restrict__ ceb1, const float* __restrict__ ceW2,
                       const float* __restrict__ ceb2, const float* __restrict__ bpW1,
                       const float* __restrict__ bpb1, const float* __restrict__ dW1,
                       const float* __restrict__ db1, const float* __restrict__ dW2,
                       const float* __restrict__ dW3, const float* __restrict__ reW1,
                       const float* __restrict__ reW2, const float* __restrict__ bpW2,
                       const float* __restrict__ bpW3, float* __restrict__ ctf,
                       float* __restrict__ ctvf, u16* __restrict__ WB) {
  __shared__ float h[256], c2[256];
  int bid = blockIdx.x, t = threadIdx.x;
  if (bid < 64) {
    int b = bid;
    float c0 = cnd[b * 2 + 0], c1 = cnd[b * 2 + 1];
    h[t] = fmaxf(c0 * ceW1[t] + c1 * ceW1[256 + t] + ceb1[t], 0.f);
    __syncthreads();
    float acc = ceb2[t];
    #pragma unroll 4
    for (int k = 0; k < 256; k++) acc += h[k] * ceW2[k * 256 + t];
    c2[t] = acc;
    __syncthreads();
    float a2 = bpb1[t];
    #pragma unroll 4
    for (int k = 0; k < 256; k++) a2 += c2[k] * bpW1[(128 + k) * 256 + t];
    ctf[b * 256 + t] = a2;
    float a3 = db1[t];
    #pragma unroll 4
    for (int k = 0; k < 256; k++) a3 += c2[k] * dW1[(64 + k) * 256 + t];
    ctvf[b * 256 + t] = a3;
    return;
  }
  int mb = bid - 64;  // 0..53
  const float* src; u16* dst; int C, S, Rv, eb; float sc = 1.f;
  if (mb < 4)       { src = dW1;          dst = WB + ODW1A; C = 64;  S = 256; Rv = 256; eb = mb; }
  else if (mb < 20) { src = dW2;          dst = WB + ODW2;  C = 256; S = 256; Rv = 256; eb = mb - 4; }
  else if (mb < 24) { src = dW3;          dst = WB + ODW3;  C = 256; S = 64;  Rv = 64;  eb = mb - 20; }
  else if (mb < 28) { src = bpW1;         dst = WB + OBPA;  C = 64;  S = 256; Rv = 256; eb = mb - 24; sc = 0.125f; }
  else if (mb < 32) { src = bpW1 + 16384; dst = WB + OBPB;  C = 64;  S = 256; Rv = 256; eb = mb - 28; sc = 0.125f; }
  else if (mb < 36) { src = reW1;         dst = WB + OREW1; C = 64;  S = 256; Rv = 256; eb = mb - 32; }
  else if (mb == 36){ src = reW2;         dst = WB + OREW2; C = 256; S = 4;   Rv = 4;   eb = 0; }
  else if (mb < 53) { src = bpW2;         dst = WB + OW2T;  C = 256; S = 256; Rv = 256; eb = mb - 37; }
  else              { src = bpW3;         dst = WB + OW3TX; C = 256; S = 4;   Rv = 4;   eb = 0; }
  #pragma unroll 4
  for (int it = 0; it < 16; it++) {
    int e = eb * 4096 + it * 256 + t;
    int r = e / C, c = e - r * C;
    float v = (r < Rv) ? src[c * S + r] * sc : 0.f;
    dst[e] = f2bf(v);
  }
}

// ---------------- per-batch adj @ in  (in/out: [B,64,K]); 512 threads (PROVEN r4) -----
template <int K>
__global__ void k_adjmm(const float* __restrict__ adj, const float* __restrict__ in,
                        float* __restrict__ out) {
  __shared__ float adj_s[64 * 64];
  __shared__ float in_s[64 * 64];
  int b = blockIdx.y, ch = blockIdx.x, t = threadIdx.x;
  const float* A = adj + b * 4096;
  for (int e = t; e < 4096; e += 512) adj_s[e] = A[e];
  const float* I = in + b * 64 * K + ch * 64;
  for (int e = t; e < 4096; e += 512) { int j = e >> 6, c = e & 63; in_s[e] = I[j * K + c]; }
  __syncthreads();
  int c = t & 63, ig = t >> 6;
  float acc[8];
  #pragma unroll
  for (int m = 0; m < 8; m++) acc[m] = 0.f;
  for (int j = 0; j < 64; j++) {
    float v = in_s[j * 64 + c];
    #pragma unroll
    for (int m = 0; m < 8; m++) acc[m] += adj_s[(ig + m * 8) * 64 + j] * v;
  }
  float* O = out + b * 64 * K + ch * 64;
  #pragma unroll
  for (int m = 0; m < 8; m++) O[(ig + m * 8) * K + c] = acc[m];
}

// ---------------- rows x [K,256] linear (+relu); 512 threads (PROVEN r4) --------------
template <int K, int MODE>
__global__ void k_lin256(const float* __restrict__ in, const float* __restrict__ W,
                         const float* __restrict__ bias, float* __restrict__ out) {
  __shared__ float in_s[16 * K];
  __shared__ float part[16 * 256];
  int t = threadIdx.x, r0 = blockIdx.x * 16;
  for (int e = t; e < 16 * K; e += 512) { int r = e / K, k = e % K; in_s[e] = in[(r0 + r) * K + k]; }
  __syncthreads();
  int col = t & 255, g = t >> 8;
  constexpr int KH = K / 2;
  float acc[16];
  #pragma unroll
  for (int r = 0; r < 16; r++) acc[r] = 0.f;
  #pragma unroll 4
  for (int k = g * KH; k < g * KH + KH; k++) {
    float w = W[k * 256 + col];
    #pragma unroll
    for (int r = 0; r < 16; r++) acc[r] += in_s[r * K + k] * w;
  }
  if (g == 1) {
    #pragma unroll
    for (int r = 0; r < 16; r++) part[r * 256 + col] = acc[r];
  }
  __syncthreads();
  if (g == 0) {
    float bv = bias[col];
    #pragma unroll
    for (int r = 0; r < 16; r++) {
      float v = acc[r] + part[r * 256 + col] + bv;
      if (MODE == 1) v = fmaxf(v, 0.f);
      out[(r0 + r) * 256 + col] = v;
    }
  }
}

// ---------------- mu / logvar heads; 512 threads (PROVEN r4) --------------------------
__global__ void k_mulv(const float* __restrict__ in, const float* __restrict__ Wmu,
                       const float* __restrict__ bmu, const float* __restrict__ Wlv,
                       const float* __restrict__ blv, float* __restrict__ mu_out,
                       float* __restrict__ lv_out) {
  __shared__ float in_s[16 * 256];
  __shared__ float part[8 * 16 * 64];
  int t = threadIdx.x, r0 = blockIdx.x * 16;
  for (int e = t; e < 4096; e += 512) in_s[e] = in[r0 * 256 + e];
  __syncthreads();
  int c = t & 63, g = t >> 6;
  int sel = g >> 2, kq = g & 3;
  const float* W = sel ? Wlv : Wmu;
  float acc[16];
  #pragma unroll
  for (int r = 0; r < 16; r++) acc[r] = 0.f;
  #pragma unroll 4
  for (int k = kq * 64; k < kq * 64 + 64; k++) {
    float w = W[k * 64 + c];
    #pragma unroll
    for (int r = 0; r < 16; r++) acc[r] += in_s[r * 256 + k] * w;
  }
  #pragma unroll
  for (int r = 0; r < 16; r++) part[(g * 16 + r) * 64 + c] = acc[r];
  __syncthreads();
  if (t < 128) {
    int cc = t & 63, s2 = t >> 6;
    const float* bb = s2 ? blv : bmu;
    float* O = s2 ? lv_out : mu_out;
    float bv = bb[cc];
    #pragma unroll
    for (int r = 0; r < 16; r++) {
      float v = bv;
      #pragma unroll
      for (int q = 0; q < 4; q++) v += part[((s2 * 4 + q) * 16 + r) * 64 + cc];
      O[(r0 + r) * 64 + cc] = v;
    }
  }
}

// =============== NT GEMM core: C[a][b] = sum_k V[a][k]*U[b][k] ========================
template <int KK, int WU, int WV, bool UG, bool VG, int ULEN, int VLEN>
__device__ __forceinline__ void mmrun(const u16* __restrict__ Up, int Uoff,
                                      const u16* __restrict__ Vp, int Voff,
                                      const char* lds, int ut0, int vt0, int lr, int lk,
                                      f32x4 (&acc)[WU][WV]) {
  #pragma unroll
  for (int kk = 0; kk < KK; kk++) {
    short8 uf[WU], vf[WV];
    #pragma unroll
    for (int i = 0; i < WU; i++) {
      int row = (ut0 + i) * 16 + lr;
      if constexpr (UG) {
        uf[i] = *(const short8*)(Up + row * ULEN + kk * 32 + lk * 8);
      } else {
        int byt = Uoff + row * (ULEN * 2) + kk * 64 + lk * 16;
        byt ^= (row & 7) << 4;
        uf[i] = *(const short8*)(lds + byt);
      }
    }
    #pragma unroll
    for (int j = 0; j < WV; j++) {
      int row = (vt0 + j) * 16 + lr;
      if constexpr (VG) {
        vf[j] = *(const short8*)(Vp + row * VLEN + kk * 32 + lk * 8);
      } else {
        int byt = Voff + row * (VLEN * 2) + kk * 64 + lk * 16;
        byt ^= (row & 7) << 4;
        vf[j] = *(const short8*)(lds + byt);
      }
    }
    #pragma unroll
    for (int i = 0; i < WU; i++)
      #pragma unroll
      for (int j = 0; j < WV; j++)
        acc[i][j] = __builtin_amdgcn_mfma_f32_16x16x32_bf16(uf[i], vf[j], acc[i][j], 0, 0, 0);
  }
}

__device__ __forceinline__ void st64(char* lds, int off, int rowlen, int crow, int ccol0,
                                     float a0, float a1, float a2, float a3) {
  uint2 pk; pk.x = cvtpk(a0, a1); pk.y = cvtpk(a2, a3);
  int byt = off + crow * (rowlen * 2) + ccol0 * 2;
  byt ^= (crow & 7) << 4;
  *(uint2*)(lds + byt) = pk;
}

template <int WU, int WV>
__device__ __forceinline__ void zacc(f32x4 (&acc)[WU][WV]) {
  #pragma unroll
  for (int i = 0; i < WU; i++)
    #pragma unroll
    for (int j = 0; j < WV; j++) acc[i][j] = (f32x4){0.f, 0.f, 0.f, 0.f};
}

// =============== k_chain2: decoder (mu -> f1 -> f2 -> feat -> P/Q/rh/val), bf16 =======
__global__ void __launch_bounds__(1024) k_chain2(
    const u16* __restrict__ WB, const float* __restrict__ mu_g,
    const float* __restrict__ ctv, const float* __restrict__ ctf,
    const float* __restrict__ db2, const float* __restrict__ db3,
    const float* __restrict__ reb1, const float* __restrict__ reb2,
    float* __restrict__ af_out, float* __restrict__ val_out,
    float* __restrict__ P, float* __restrict__ Q) {
  __shared__ char L[65536];
  constexpr int S2 = 0, S3 = 32768;
  int b = blockIdx.x, t = threadIdx.x;
  int w = t >> 6, lane = t & 63, lr = lane & 15, lk = lane >> 4;

  // ---- stage mu (global fp32) -> S3 bf16 [64i][64L] swizzled ----
  {
    int r = t >> 4, c0 = (t & 15) * 4;
    float4 v = *(const float4*)(mu_g + ((b * 64 + r) * 64 + c0));
    st64(L, S3, 64, r, c0, v.x, v.y, v.z, v.w);
  }
  __syncthreads();
  // ---- f1 = relu(mu@dW1a + ctv) -> S2 [64i][256n] ----
  {
    f32x4 a[2][2]; zacc(a);
    int ut0 = (w & 7) * 2, vt0 = (w >> 3) * 2;
    mmrun<2, 2, 2, true, false, 64, 64>(WB + ODW1A, 0, WB, S3, L, ut0, vt0, lr, lk, a);
    #pragma unroll
    for (int j = 0; j < 2; j++) {
      int crow = (vt0 + j) * 16 + lr;
      #pragma unroll
      for (int i = 0; i < 2; i++) {
        int cc = (ut0 + i) * 16 + lk * 4;
        float4 cv = *(const float4*)(ctv + b * 256 + cc);
        st64(L, S2, 256, crow, cc, fmaxf(a[i][j][0] + cv.x, 0.f), fmaxf(a[i][j][1] + cv.y, 0.f),
             fmaxf(a[i][j][2] + cv.z, 0.f), fmaxf(a[i][j][3] + cv.w, 0.f));
      }
    }
  }
  __syncthreads();
  // ---- f2 = relu(f1@dW2 + db2) -> S3 [64i][256n] ----
  {
    f32x4 a[2][2]; zacc(a);
    int ut0 = (w & 7) * 2, vt0 = (w >> 3) * 2;
    mmrun<8, 2, 2, true, false, 256, 256>(WB + ODW2, 0, WB, S2, L, ut0, vt0, lr, lk, a);
    #pragma unroll
    for (int j = 0; j < 2; j++) {
      int crow = (vt0 + j) * 16 + lr;
      #pragma unroll
      for (int i = 0; i < 2; i++) {
        int cc = (ut0 + i) * 16 + lk * 4;
        float4 bv = *(const float4*)(db2 + cc);
        st64(L, S3, 256, crow, cc, fmaxf(a[i][j][0] + bv.x, 0.f), fmaxf(a[i][j][1] + bv.y, 0.f),
             fmaxf(a[i][j][2] + bv.z, 0.f), fmaxf(a[i][j][3] + bv.w, 0.f));
      }
    }
  }
  __syncthreads();
  // ---- feat = sigmoid(f2@dW3 + db3) -> S2 bf16 [64i][64d]; af_out = feat*0.125 ----
  {
    f32x4 a[1][1]; zacc(a);
    int ut = w & 3, vt = w >> 2;
    mmrun<8, 1, 1, true, false, 256, 256>(WB + ODW3, 0, WB, S3, L, ut, vt, lr, lk, a);
    int crow = vt * 16 + lr, cc = ut * 16 + lk * 4;
    float4 bv = *(const float4*)(db3 + cc);
    float s0 = 1.f / (1.f + expf(-(a[0][0][0] + bv.x)));
    float s1 = 1.f / (1.f + expf(-(a[0][0][1] + bv.y)));
    float s2 = 1.f / (1.f + expf(-(a[0][0][2] + bv.z)));
    float s3 = 1.f / (1.f + expf(-(a[0][0][3] + bv.w)));
    *(float4*)(af_out + ((b * 64 + crow) * 64 + cc)) =
        make_float4(s0 * 0.125f, s1 * 0.125f, s2 * 0.125f, s3 * 0.125f);
    st64(L, S2, 64, crow, cc, s0, s1, s2, s3);
  }
  __syncthreads();
  // ---- P = 0.125*feat@bpW1a + ct ; Q = 0.125*feat@bpW1b  -> global fp32 ----
  {
    f32x4 a[2][4]; zacc(a);
    int ut0 = (w & 7) * 2;
    int sel = w >> 3;
    const u16* Up = WB + (sel ? OBPB : OBPA);
    mmrun<2, 2, 4, true, false, 64, 64>(Up, 0, WB, S2, L, ut0, 0, lr, lk, a);
    float* out = sel ? Q : P;
    #pragma unroll
    for (int i = 0; i < 2; i++) {
      int cc = (ut0 + i) * 16 + lk * 4;
      float4 cv = make_float4(0.f, 0.f, 0.f, 0.f);
      if (sel == 0) cv = *(const float4*)(ctf + b * 256 + cc);
      #pragma unroll
      for (int j = 0; j < 4; j++) {
        int crow = j * 16 + lr;
        *(float4*)(out + ((b * 64 + crow) * 256 + cc)) =
            make_float4(a[i][j][0] + cv.x, a[i][j][1] + cv.y, a[i][j][2] + cv.z, a[i][j][3] + cv.w);
      }
    }
  }
  // ---- rh = relu(feat@reW1 + reb1) -> S3 [64i][256n] ----
  {
    f32x4 a[2][2]; zacc(a);
    int ut0 = (w & 7) * 2, vt0 = (w >> 3) * 2;
    mmrun<2, 2, 2, true, false, 64, 64>(WB + OREW1, 0, WB, S2, L, ut0, vt0, lr, lk, a);
    #pragma unroll
    for (int j = 0; j < 2; j++) {
      int crow = (vt0 + j) * 16 + lr;
      #pragma unroll
      for (int i = 0; i < 2; i++) {
        int cc = (ut0 + i) * 16 + lk * 4;
        float4 bv = *(const float4*)(reb1 + cc);
        st64(L, S3, 256, crow, cc, fmaxf(a[i][j][0] + bv.x, 0.f), fmaxf(a[i][j][1] + bv.y, 0.f),
             fmaxf(a[i][j][2] + bv.z, 0.f), fmaxf(a[i][j][3] + bv.w, 0.f));
      }
    }
  }
  __syncthreads();
  // ---- val = 4*sigmoid(rh@reW2 + reb2) -> global fp32 ----
  if (w < 4) {
    f32x4 a[1][1]; zacc(a);
    mmrun<8, 1, 1, true, false, 256, 256>(WB + OREW2, 0, WB, S3, L, 0, w, lr, lk, a);
    if (lk == 0) {
      float4 rb = *(const float4*)reb2;
      float v0 = 4.f / (1.f + expf(-(a[0][0][0] + rb.x)));
      float v1 = 4.f / (1.f + expf(-(a[0][0][1] + rb.y)));
      float v2 = 4.f / (1.f + expf(-(a[0][0][2] + rb.z)));
      float v3 = 4.f / (1.f + expf(-(a[0][0][3] + rb.w)));
      *(float4*)(val_out + (b * 64 + w * 16 + lr) * 4) = make_float4(v0, v1, v2, v3);
    }
  }
}

// =============== fused bond MLP (PROVEN r5: 32KB LDS, parallel softmax) ===============
__global__ void k_bond(const float* __restrict__ P, const float* __restrict__ Q,
                       const u16* __restrict__ W2T, const float* __restrict__ b2,
                       const u16* __restrict__ W3Tx, const float* __restrict__ b3,
                       float* __restrict__ bp_out) {
  __shared__ u16 G[64 * 256];
  int i = blockIdx.x, b = blockIdx.y;
  int t = threadIdx.x;
  int lane = t & 63, w = t >> 6;
  int lr = lane & 15, lk = lane >> 4;

  {
    int colg = t & 63, rq = t >> 6;
    float4 pv = *(const float4*)(P + (b * 64 + i) * 256 + colg * 4);
    const float* Qb = Q + b * 64 * 256;
    #pragma unroll 4
    for (int r = rq * 16; r < rq * 16 + 16; r++) {
      float4 q4 = *(const float4*)(Qb + r * 256 + colg * 4);
      float v0 = fmaxf(pv.x + q4.x, 0.f), v1 = fmaxf(pv.y + q4.y, 0.f);
      float v2 = fmaxf(pv.z + q4.z, 0.f), v3 = fmaxf(pv.w + q4.w, 0.f);
      uint2 pk;
      pk.x = cvtpk(v0, v1);
      pk.y = cvtpk(v2, v3);
      int byt = (r * 512 + colg * 8) ^ ((r & 7) << 4);
      *(uint2*)((char*)G + byt) = pk;
    }
  }
  __syncthreads();

  f32x4 zero4 = {0.f, 0.f, 0.f, 0.f};
  f32x4 acc[4][4];
  #pragma unroll
  for (int ni = 0; ni < 4; ni++)
    #pragma unroll
    for (int mi = 0; mi < 4; mi++) acc[ni][mi] = zero4;

  for (int kk = 0; kk < 8; kk++) {
    short8 a[4], bw[4];
    #pragma unroll
    for (int mi = 0; mi < 4; mi++) {
      int row = mi * 16 + lr;
      int byt = (row * 512 + kk * 64 + lk * 16) ^ ((row & 7) << 4);
      a[mi] = *(const short8*)((const char*)G + byt);
    }
    #pragma unroll
    for (int ni = 0; ni < 4; ni++) {
      int col = w * 64 + ni * 16 + lr;
      bw[ni] = *(const short8*)(W2T + col * 256 + kk * 32 + lk * 8);
    }
    #pragma unroll
    for (int ni = 0; ni < 4; ni++)
      #pragma unroll
      for (int mi = 0; mi < 4; mi++)
        acc[ni][mi] = __builtin_amdgcn_mfma_f32_16x16x32_bf16(bw[ni], a[mi], acc[ni][mi], 0, 0, 0);
  }
  __syncthreads();

  #pragma unroll
  for (int ni = 0; ni < 4; ni++) {
    int col0 = w * 64 + ni * 16 + lk * 4;
    float4 bb = *(const float4*)(b2 + col0);
    #pragma unroll
    for (int mi = 0; mi < 4; mi++) {
      int grow = mi * 16 + lr;
      float v0 = fmaxf(acc[ni][mi][0] + bb.x, 0.f);
      float v1 = fmaxf(acc[ni][mi][1] + bb.y, 0.f);
      float v2 = fmaxf(acc[ni][mi][2] + bb.z, 0.f);
      float v3 = fmaxf(acc[ni][mi][3] + bb.w, 0.f);
      uint2 pk;
      pk.x = cvtpk(v0, v1);
      pk.y = cvtpk(v2, v3);
      int byt = (grow * 512 + col0 * 2) ^ ((grow & 7) << 4);
      *(uint2*)((char*)G + byt) = pk;
    }
  }
  __syncthreads();

  f32x4 acc2[4];
  #pragma unroll
  for (int mi = 0; mi < 4; mi++) acc2[mi] = zero4;
  #pragma unroll
  for (int kk = 0; kk < 2; kk++) {
    short8 bw2 = *(const short8*)(W3Tx + lr * 256 + w * 64 + kk * 32 + lk * 8);
    #pragma unroll
    for (int mi = 0; mi < 4; mi++) {
      int row = mi * 16 + lr;
      int kbyte = (w * 64 + kk * 32 + lk * 8) * 2;
      int byt = (row * 512 + kbyte) ^ ((row & 7) << 4);
      short8 a = *(const short8*)((const char*)G + byt);
      acc2[mi] = __builtin_amdgcn_mfma_f32_16x16x32_bf16(a, bw2, acc2[mi], 0, 0, 0);
    }
  }
  __syncthreads();
  float* pf = (float*)G;
  if (lr < 4) {
    #pragma unroll
    for (int mi = 0; mi < 4; mi++)
      #pragma unroll
      for (int rg = 0; rg < 4; rg++) {
        int row = mi * 16 + lk * 4 + rg;
        pf[(w * 64 + row) * 4 + lr] = acc2[mi][rg];
      }
  }
  __syncthreads();

  {
    int r = t >> 2, c = t & 3;
    float lv = pf[(0 * 64 + r) * 4 + c] + pf[(1 * 64 + r) * 4 + c] +
               pf[(2 * 64 + r) * 4 + c] + pf[(3 * 64 + r) * 4 + c] + b3[c];
    float m = fmaxf(lv, __shfl_xor(lv, 1));
    m = fmaxf(m, __shfl_xor(m, 2));
    float e = expf(lv - m);
    float s = e + __shfl_xor(e, 1);
    s += __shfl_xor(s, 2);
    bp_out[((b * 64 + i) * 64 + r) * 4 + c] = e / s;
  }
}

extern "C" void kernel_launch(void* const* d_in, const int* in_sizes, int n_in,
                              void* d_out, int out_size, void* d_ws, size_t ws_size,
                              hipStream_t stream) {
  const float* x    = (const float*)d_in[0];
  const float* adj  = (const float*)d_in[1];
  const float* cnd  = (const float*)d_in[2];
  const float* gc1W = (const float*)d_in[3];
  const float* gc1b = (const float*)d_in[4];
  const float* gc2W = (const float*)d_in[5];
  const float* gc2b = (const float*)d_in[6];
  const float* gmuW = (const float*)d_in[7];
  const float* gmub = (const float*)d_in[8];
  const float* glvW = (const float*)d_in[9];
  const float* glvb = (const float*)d_in[10];
  const float* ceW1 = (const float*)d_in[11];
  const float* ceb1 = (const float*)d_in[12];
  const float* ceW2 = (const float*)d_in[13];
  const float* ceb2 = (const float*)d_in[14];
  const float* dW1  = (const float*)d_in[15];
  const float* db1  = (const float*)d_in[16];
  const float* dW2  = (const float*)d_in[17];
  const float* db2  = (const float*)d_in[18];
  const float* dW3  = (const float*)d_in[19];
  const float* db3  = (const float*)d_in[20];
  // d_in[21..24] (at_*) are dead: mean(softmax) == 1/8 exactly
  const float* bpW1 = (const float*)d_in[25];
  const float* bpb1 = (const float*)d_in[26];
  const float* bpW2 = (const float*)d_in[27];
  const float* bpb2 = (const float*)d_in[28];
  const float* bpW3 = (const float*)d_in[29];
  const float* bpb3 = (const float*)d_in[30];
  const float* reW1 = (const float*)d_in[31];
  const float* reb1 = (const float*)d_in[32];
  const float* reW2 = (const float*)d_in[33];
  const float* reb2 = (const float*)d_in[34];

  float* out = (float*)d_out;
  float* af_out  = out;            // [64,64,64]
  float* bp_out  = out + 262144;   // [64,64,64,4]
  float* val_out = out + 1310720;  // [64,64,4]
  float* mu_out  = out + 1327104;  // [64,64,64]
  float* lv_out  = out + 1589248;  // [64,64,64]

  float* ws   = (float*)d_ws;
  float* ctf  = ws;                 // 16384
  float* ctv  = ws + 16384;         // 16384
  float* buf1 = ws + 32768;         // 1048576
  float* buf2 = buf1 + 1048576;     // 1048576  (also ax; later P)
  float* buf3 = buf2 + 1048576;     // 1048576  (later Q)
  u16*   WB   = (u16*)(buf3 + 1048576);  // 221184 u16

  k_prep<<<118, 256, 0, stream>>>(cnd, ceW1, ceb1, ceW2, ceb2, bpW1, bpb1, dW1, db1,
                                  dW2, dW3, reW1, reW2, bpW2, bpW3, ctf, ctv, WB);
  k_adjmm<64><<<dim3(1, 64), 512, 0, stream>>>(adj, x, buf2);              // ax
  k_lin256<64, 1><<<256, 512, 0, stream>>>(buf2, gc1W, gc1b, buf1);        // h1
  k_adjmm<256><<<dim3(4, 64), 512, 0, stream>>>(adj, buf1, buf2);          // ah1
  k_lin256<256, 1><<<256, 512, 0, stream>>>(buf2, gc2W, gc2b, buf3);       // h2
  k_adjmm<256><<<dim3(4, 64), 512, 0, stream>>>(adj, buf3, buf1);          // ah2
  k_mulv<<<256, 512, 0, stream>>>(buf1, gmuW, gmub, glvW, glvb, mu_out, lv_out);
  k_chain2<<<64, 1024, 0, stream>>>(WB, mu_out, ctv, ctf, db2, db3, reb1, reb2,
                                    af_out, val_out, buf2, buf3);          // P=buf2 Q=buf3
  k_bond<<<dim3(64, 64), 256, 0, stream>>>(buf2, buf3, WB + OW2T, bpb2, WB + OW3TX, bpb3, bp_out);
}

// Round 7
// 222.490 us; speedup vs baseline: 1.3718x; 1.0250x over previous
//
#include <hip/hip_runtime.h>

typedef short short8 __attribute__((ext_vector_type(8)));
typedef float f32x4 __attribute__((ext_vector_type(4)));
typedef unsigned short u16;
typedef unsigned int u32;

__device__ __forceinline__ u16 f2bf(float f) {
  union { float f; u32 u; } x; x.f = f;
  u32 u = x.u;
  u32 r = (u + 0x7FFFu + ((u >> 16) & 1u)) >> 16;
  return (u16)r;
}

__device__ __forceinline__ u32 cvtpk(float lo, float hi) {
  u32 r;
  asm("v_cvt_pk_bf16_f32 %0, %1, %2" : "=v"(r) : "v"(lo), "v"(hi));
  return r;
}

// ---- WB bf16-region offsets (u16 units) — decoder + bond weights only ----
#define OW2T   0        // bond W2^T      [256][256]
#define OW3TX  65536    // bond W3 padT   [16][256]
#define ODW1A  69632    // dW1[0:64]^T    [256][64]
#define ODW2   86016    // dW2^T          [256][256]
#define ODW3   151552   // dW3^T          [64][256]
#define OBPA   167936   // bpW1[0:64]^T   [256][64]  x0.125
#define OBPB   184320   // bpW1[64:128]^T [256][64]  x0.125
#define OREW1  200704   // reW1^T         [256][64]
#define OREW2  217088   // reW2 padT      [16][256]
// total 221184 u16

// =============== k_prep: ctf/ctv (blocks 0..63) + weight transposes (64..117) =========
__global__ void k_prep(const float* __restrict__ cnd, const float* __restrict__ ceW1,
                       const float* __restrict__ ceb1, const float* __restrict__ ceW2,
                       const float* __restrict__ ceb2, const float* __restrict__ bpW1,
                       const float* __restrict__ bpb1, const float* __restrict__ dW1,
                       const float* __restrict__ db1, const float* __restrict__ dW2,
                       const float* __restrict__ dW3, const float* __restrict__ reW1,
                       const float* __restrict__ reW2, const float* __restrict__ bpW2,
                       const float* __restrict__ bpW3, float* __restrict__ ctf,
                       float* __restrict__ ctvf, u16* __restrict__ WB) {
  __shared__ float h[256], c2[256];
  int bid = blockIdx.x, t = threadIdx.x;
  if (bid < 64) {
    int b = bid;
    float c0 = cnd[b * 2 + 0], c1 = cnd[b * 2 + 1];
    h[t] = fmaxf(c0 * ceW1[t] + c1 * ceW1[256 + t] + ceb1[t], 0.f);
    __syncthreads();
    float acc = ceb2[t];
    #pragma unroll 4
    for (int k = 0; k < 256; k++) acc += h[k] * ceW2[k * 256 + t];
    c2[t] = acc;
    __syncthreads();
    float a2 = bpb1[t];
    #pragma unroll 4
    for (int k = 0; k < 256; k++) a2 += c2[k] * bpW1[(128 + k) * 256 + t];
    ctf[b * 256 + t] = a2;
    float a3 = db1[t];
    #pragma unroll 4
    for (int k = 0; k < 256; k++) a3 += c2[k] * dW1[(64 + k) * 256 + t];
    ctvf[b * 256 + t] = a3;
    return;
  }
  int mb = bid - 64;  // 0..53
  const float* src; u16* dst; int C, S, Rv, eb; float sc = 1.f;
  if (mb < 4)       { src = dW1;          dst = WB + ODW1A; C = 64;  S = 256; Rv = 256; eb = mb; }
  else if (mb < 20) { src = dW2;          dst = WB + ODW2;  C = 256; S = 256; Rv = 256; eb = mb - 4; }
  else if (mb < 24) { src = dW3;          dst = WB + ODW3;  C = 256; S = 64;  Rv = 64;  eb = mb - 20; }
  else if (mb < 28) { src = bpW1;         dst = WB + OBPA;  C = 64;  S = 256; Rv = 256; eb = mb - 24; sc = 0.125f; }
  else if (mb < 32) { src = bpW1 + 16384; dst = WB + OBPB;  C = 64;  S = 256; Rv = 256; eb = mb - 28; sc = 0.125f; }
  else if (mb < 36) { src = reW1;         dst = WB + OREW1; C = 64;  S = 256; Rv = 256; eb = mb - 32; }
  else if (mb == 36){ src = reW2;         dst = WB + OREW2; C = 256; S = 4;   Rv = 4;   eb = 0; }
  else if (mb < 53) { src = bpW2;         dst = WB + OW2T;  C = 256; S = 256; Rv = 256; eb = mb - 37; }
  else              { src = bpW3;         dst = WB + OW3TX; C = 256; S = 4;   Rv = 4;   eb = 0; }
  #pragma unroll 4
  for (int it = 0; it < 16; it++) {
    int e = eb * 4096 + it * 256 + t;
    int r = e / C, c = e - r * C;
    float v = (r < Rv) ? src[c * S + r] * sc : 0.f;
    dst[e] = f2bf(v);
  }
}

// ---------------- per-batch adj @ in  (in/out: [B,64,K]); 512 threads (PROVEN r4) -----
template <int K>
__global__ void k_adjmm(const float* __restrict__ adj, const float* __restrict__ in,
                        float* __restrict__ out) {
  __shared__ float adj_s[64 * 64];
  __shared__ float in_s[64 * 64];
  int b = blockIdx.y, ch = blockIdx.x, t = threadIdx.x;
  const float* A = adj + b * 4096;
  for (int e = t; e < 4096; e += 512) adj_s[e] = A[e];
  const float* I = in + b * 64 * K + ch * 64;
  for (int e = t; e < 4096; e += 512) { int j = e >> 6, c = e & 63; in_s[e] = I[j * K + c]; }
  __syncthreads();
  int c = t & 63, ig = t >> 6;
  float acc[8];
  #pragma unroll
  for (int m = 0; m < 8; m++) acc[m] = 0.f;
  for (int j = 0; j < 64; j++) {
    float v = in_s[j * 64 + c];
    #pragma unroll
    for (int m = 0; m < 8; m++) acc[m] += adj_s[(ig + m * 8) * 64 + j] * v;
  }
  float* O = out + b * 64 * K + ch * 64;
  #pragma unroll
  for (int m = 0; m < 8; m++) O[(ig + m * 8) * K + c] = acc[m];
}

// ---------------- rows x [K,256] linear (+relu); 512 threads (PROVEN r4) --------------
template <int K, int MODE>
__global__ void k_lin256(const float* __restrict__ in, const float* __restrict__ W,
                         const float* __restrict__ bias, float* __restrict__ out) {
  __shared__ float in_s[16 * K];
  __shared__ float part[16 * 256];
  int t = threadIdx.x, r0 = blockIdx.x * 16;
  for (int e = t; e < 16 * K; e += 512) { int r = e / K, k = e % K; in_s[e] = in[(r0 + r) * K + k]; }
  __syncthreads();
  int col = t & 255, g = t >> 8;
  constexpr int KH = K / 2;
  float acc[16];
  #pragma unroll
  for (int r = 0; r < 16; r++) acc[r] = 0.f;
  #pragma unroll 4
  for (int k = g * KH; k < g * KH + KH; k++) {
    float w = W[k * 256 + col];
    #pragma unroll
    for (int r = 0; r < 16; r++) acc[r] += in_s[r * K + k] * w;
  }
  if (g == 1) {
    #pragma unroll
    for (int r = 0; r < 16; r++) part[r * 256 + col] = acc[r];
  }
  __syncthreads();
  if (g == 0) {
    float bv = bias[col];
    #pragma unroll
    for (int r = 0; r < 16; r++) {
      float v = acc[r] + part[r * 256 + col] + bv;
      if (MODE == 1) v = fmaxf(v, 0.f);
      out[(r0 + r) * 256 + col] = v;
    }
  }
}

// ---------------- mu / logvar heads; 512 threads (PROVEN r4) --------------------------
__global__ void k_mulv(const float* __restrict__ in, const float* __restrict__ Wmu,
                       const float* __restrict__ bmu, const float* __restrict__ Wlv,
                       const float* __restrict__ blv, float* __restrict__ mu_out,
                       float* __restrict__ lv_out) {
  __shared__ float in_s[16 * 256];
  __shared__ float part[8 * 16 * 64];
  int t = threadIdx.x, r0 = blockIdx.x * 16;
  for (int e = t; e < 4096; e += 512) in_s[e] = in[r0 * 256 + e];
  __syncthreads();
  int c = t & 63, g = t >> 6;
  int sel = g >> 2, kq = g & 3;
  const float* W = sel ? Wlv : Wmu;
  float acc[16];
  #pragma unroll
  for (int r = 0; r < 16; r++) acc[r] = 0.f;
  #pragma unroll 4
  for (int k = kq * 64; k < kq * 64 + 64; k++) {
    float w = W[k * 64 + c];
    #pragma unroll
    for (int r = 0; r < 16; r++) acc[r] += in_s[r * 256 + k] * w;
  }
  #pragma unroll
  for (int r = 0; r < 16; r++) part[(g * 16 + r) * 64 + c] = acc[r];
  __syncthreads();
  if (t < 128) {
    int cc = t & 63, s2 = t >> 6;
    const float* bb = s2 ? blv : bmu;
    float* O = s2 ? lv_out : mu_out;
    float bv = bb[cc];
    #pragma unroll
    for (int r = 0; r < 16; r++) {
      float v = bv;
      #pragma unroll
      for (int q = 0; q < 4; q++) v += part[((s2 * 4 + q) * 16 + r) * 64 + cc];
      O[(r0 + r) * 64 + cc] = v;
    }
  }
}

// =============== NT GEMM core: C[a][b] = sum_k V[a][k]*U[b][k] ========================
template <int KK, int WU, int WV, bool UG, bool VG, int ULEN, int VLEN>
__device__ __forceinline__ void mmrun(const u16* __restrict__ Up, int Uoff,
                                      const u16* __restrict__ Vp, int Voff,
                                      const char* lds, int ut0, int vt0, int lr, int lk,
                                      f32x4 (&acc)[WU][WV]) {
  #pragma unroll
  for (int kk = 0; kk < KK; kk++) {
    short8 uf[WU], vf[WV];
    #pragma unroll
    for (int i = 0; i < WU; i++) {
      int row = (ut0 + i) * 16 + lr;
      if constexpr (UG) {
        uf[i] = *(const short8*)(Up + row * ULEN + kk * 32 + lk * 8);
      } else {
        int byt = Uoff + row * (ULEN * 2) + kk * 64 + lk * 16;
        byt ^= (row & 7) << 4;
        uf[i] = *(const short8*)(lds + byt);
      }
    }
    #pragma unroll
    for (int j = 0; j < WV; j++) {
      int row = (vt0 + j) * 16 + lr;
      if constexpr (VG) {
        vf[j] = *(const short8*)(Vp + row * VLEN + kk * 32 + lk * 8);
      } else {
        int byt = Voff + row * (VLEN * 2) + kk * 64 + lk * 16;
        byt ^= (row & 7) << 4;
        vf[j] = *(const short8*)(lds + byt);
      }
    }
    #pragma unroll
    for (int i = 0; i < WU; i++)
      #pragma unroll
      for (int j = 0; j < WV; j++)
        acc[i][j] = __builtin_amdgcn_mfma_f32_16x16x32_bf16(uf[i], vf[j], acc[i][j], 0, 0, 0);
  }
}

__device__ __forceinline__ void st64(char* lds, int off, int rowlen, int crow, int ccol0,
                                     float a0, float a1, float a2, float a3) {
  uint2 pk; pk.x = cvtpk(a0, a1); pk.y = cvtpk(a2, a3);
  int byt = off + crow * (rowlen * 2) + ccol0 * 2;
  byt ^= (crow & 7) << 4;
  *(uint2*)(lds + byt) = pk;
}

template <int WU, int WV>
__device__ __forceinline__ void zacc(f32x4 (&acc)[WU][WV]) {
  #pragma unroll
  for (int i = 0; i < WU; i++)
    #pragma unroll
    for (int j = 0; j < WV; j++) acc[i][j] = (f32x4){0.f, 0.f, 0.f, 0.f};
}

// =============== k_chain2: decoder (mu -> f1 -> f2 -> feat -> P/Q/rh/val), bf16 =======
__global__ void __launch_bounds__(1024) k_chain2(
    const u16* __restrict__ WB, const float* __restrict__ mu_g,
    const float* __restrict__ ctv, const float* __restrict__ ctf,
    const float* __restrict__ db2, const float* __restrict__ db3,
    const float* __restrict__ reb1, const float* __restrict__ reb2,
    float* __restrict__ af_out, float* __restrict__ val_out,
    float* __restrict__ P, float* __restrict__ Q) {
  __shared__ char L[65536];
  constexpr int S2 = 0, S3 = 32768;
  int b = blockIdx.x, t = threadIdx.x;
  int w = t >> 6, lane = t & 63, lr = lane & 15, lk = lane >> 4;

  // ---- stage mu (global fp32) -> S3 bf16 [64i][64L] swizzled ----
  {
    int r = t >> 4, c0 = (t & 15) * 4;
    float4 v = *(const float4*)(mu_g + ((b * 64 + r) * 64 + c0));
    st64(L, S3, 64, r, c0, v.x, v.y, v.z, v.w);
  }
  __syncthreads();
  // ---- f1 = relu(mu@dW1a + ctv) -> S2 [64i][256n] ----
  {
    f32x4 a[2][2]; zacc(a);
    int ut0 = (w & 7) * 2, vt0 = (w >> 3) * 2;
    mmrun<2, 2, 2, true, false, 64, 64>(WB + ODW1A, 0, WB, S3, L, ut0, vt0, lr, lk, a);
    #pragma unroll
    for (int j = 0; j < 2; j++) {
      int crow = (vt0 + j) * 16 + lr;
      #pragma unroll
      for (int i = 0; i < 2; i++) {
        int cc = (ut0 + i) * 16 + lk * 4;
        float4 cv = *(const float4*)(ctv + b * 256 + cc);
        st64(L, S2, 256, crow, cc, fmaxf(a[i][j][0] + cv.x, 0.f), fmaxf(a[i][j][1] + cv.y, 0.f),
             fmaxf(a[i][j][2] + cv.z, 0.f), fmaxf(a[i][j][3] + cv.w, 0.f));
      }
    }
  }
  __syncthreads();
  // ---- f2 = relu(f1@dW2 + db2) -> S3 [64i][256n] ----
  {
    f32x4 a[2][2]; zacc(a);
    int ut0 = (w & 7) * 2, vt0 = (w >> 3) * 2;
    mmrun<8, 2, 2, true, false, 256, 256>(WB + ODW2, 0, WB, S2, L, ut0, vt0, lr, lk, a);
    #pragma unroll
    for (int j = 0; j < 2; j++) {
      int crow = (vt0 + j) * 16 + lr;
      #pragma unroll
      for (int i = 0; i < 2; i++) {
        int cc = (ut0 + i) * 16 + lk * 4;
        float4 bv = *(const float4*)(db2 + cc);
        st64(L, S3, 256, crow, cc, fmaxf(a[i][j][0] + bv.x, 0.f), fmaxf(a[i][j][1] + bv.y, 0.f),
             fmaxf(a[i][j][2] + bv.z, 0.f), fmaxf(a[i][j][3] + bv.w, 0.f));
      }
    }
  }
  __syncthreads();
  // ---- feat = sigmoid(f2@dW3 + db3) -> S2 bf16 [64i][64d]; af_out = feat*0.125 ----
  {
    f32x4 a[1][1]; zacc(a);
    int ut = w & 3, vt = w >> 2;
    mmrun<8, 1, 1, true, false, 256, 256>(WB + ODW3, 0, WB, S3, L, ut, vt, lr, lk, a);
    int crow = vt * 16 + lr, cc = ut * 16 + lk * 4;
    float4 bv = *(const float4*)(db3 + cc);
    float s0 = 1.f / (1.f + expf(-(a[0][0][0] + bv.x)));
    float s1 = 1.f / (1.f + expf(-(a[0][0][1] + bv.y)));
    float s2 = 1.f / (1.f + expf(-(a[0][0][2] + bv.z)));
    float s3 = 1.f / (1.f + expf(-(a[0][0][3] + bv.w)));
    *(float4*)(af_out + ((b * 64 + crow) * 64 + cc)) =
        make_float4(s0 * 0.125f, s1 * 0.125f, s2 * 0.125f, s3 * 0.125f);
    st64(L, S2, 64, crow, cc, s0, s1, s2, s3);
  }
  __syncthreads();
  // ---- P = 0.125*feat@bpW1a + ct ; Q = 0.125*feat@bpW1b  -> global fp32 ----
  {
    f32x4 a[2][4]; zacc(a);
    int ut0 = (w & 7) * 2;
    int sel = w >> 3;
    const u16* Up = WB + (sel ? OBPB : OBPA);
    mmrun<2, 2, 4, true, false, 64, 64>(Up, 0, WB, S2, L, ut0, 0, lr, lk, a);
    float* out = sel ? Q : P;
    #pragma unroll
    for (int i = 0; i < 2; i++) {
      int cc = (ut0 + i) * 16 + lk * 4;
      float4 cv = make_float4(0.f, 0.f, 0.f, 0.f);
      if (sel == 0) cv = *(const float4*)(ctf + b * 256 + cc);
      #pragma unroll
      for (int j = 0; j < 4; j++) {
        int crow = j * 16 + lr;
        *(float4*)(out + ((b * 64 + crow) * 256 + cc)) =
            make_float4(a[i][j][0] + cv.x, a[i][j][1] + cv.y, a[i][j][2] + cv.z, a[i][j][3] + cv.w);
      }
    }
  }
  // ---- rh = relu(feat@reW1 + reb1) -> S3 [64i][256n] ----
  {
    f32x4 a[2][2]; zacc(a);
    int ut0 = (w & 7) * 2, vt0 = (w >> 3) * 2;
    mmrun<2, 2, 2, true, false, 64, 64>(WB + OREW1, 0, WB, S2, L, ut0, vt0, lr, lk, a);
    #pragma unroll
    for (int j = 0; j < 2; j++) {
      int crow = (vt0 + j) * 16 + lr;
      #pragma unroll
      for (int i = 0; i < 2; i++) {
        int cc = (ut0 + i) * 16 + lk * 4;
        float4 bv = *(const float4*)(reb1 + cc);
        st64(L, S3, 256, crow, cc, fmaxf(a[i][j][0] + bv.x, 0.f), fmaxf(a[i][j][1] + bv.y, 0.f),
             fmaxf(a[i][j][2] + bv.z, 0.f), fmaxf(a[i][j][3] + bv.w, 0.f));
      }
    }
  }
  __syncthreads();
  // ---- val = 4*sigmoid(rh@reW2 + reb2) -> global fp32 ----
  if (w < 4) {
    f32x4 a[1][1]; zacc(a);
    mmrun<8, 1, 1, true, false, 256, 256>(WB + OREW2, 0, WB, S3, L, 0, w, lr, lk, a);
    if (lk == 0) {
      float4 rb = *(const float4*)reb2;
      float v0 = 4.f / (1.f + expf(-(a[0][0][0] + rb.x)));
      float v1 = 4.f / (1.f + expf(-(a[0][0][1] + rb.y)));
      float v2 = 4.f / (1.f + expf(-(a[0][0][2] + rb.z)));
      float v3 = 4.f / (1.f + expf(-(a[0][0][3] + rb.w)));
      *(float4*)(val_out + (b * 64 + w * 16 + lr) * 4) = make_float4(v0, v1, v2, v3);
    }
  }
}

// =============== fused bond MLP v3: 8 waves, XCD swizzle, K-split GEMM2 ===============
__global__ void __launch_bounds__(512) k_bond(
    const float* __restrict__ P, const float* __restrict__ Q,
    const u16* __restrict__ W2T, const float* __restrict__ b2,
    const u16* __restrict__ W3Tx, const float* __restrict__ b3,
    float* __restrict__ bp_out) {
  __shared__ u16 G[64 * 256];  // 32KB bf16, XOR-swizzled rows
  // XCD-aware decode: same-b blocks co-resident on one XCD (L2 locality for Q[b])
  int flat = blockIdx.x;
  int xcd = flat & 7, kf = flat >> 3;
  int b = xcd * 8 + (kf >> 6);
  int i = kf & 63;
  int t = threadIdx.x;
  int lane = t & 63, w = t >> 6;  // w 0..7
  int lr = lane & 15, lk = lane >> 4;

  // ---- build G1[j][k] = relu(P'[b,i,k] + Q[b,j,k]) ; 512 threads, 8 rows each ----
  {
    int colg = t & 63, rq = t >> 6;
    float4 pv = *(const float4*)(P + (b * 64 + i) * 256 + colg * 4);
    const float* Qb = Q + b * 64 * 256;
    #pragma unroll 4
    for (int r = rq * 8; r < rq * 8 + 8; r++) {
      float4 q4 = *(const float4*)(Qb + r * 256 + colg * 4);
      float v0 = fmaxf(pv.x + q4.x, 0.f), v1 = fmaxf(pv.y + q4.y, 0.f);
      float v2 = fmaxf(pv.z + q4.z, 0.f), v3 = fmaxf(pv.w + q4.w, 0.f);
      uint2 pk;
      pk.x = cvtpk(v0, v1);
      pk.y = cvtpk(v2, v3);
      int byt = (r * 512 + colg * 8) ^ ((r & 7) << 4);
      *(uint2*)((char*)G + byt) = pk;
    }
  }
  __syncthreads();

  // ---- GEMM1 (swapped): wave owns 32 out-cols; acc[ni][mi] = 4 consec cols of a row --
  f32x4 zero4 = {0.f, 0.f, 0.f, 0.f};
  f32x4 acc[2][4];
  #pragma unroll
  for (int ni = 0; ni < 2; ni++)
    #pragma unroll
    for (int mi = 0; mi < 4; mi++) acc[ni][mi] = zero4;

  for (int kk = 0; kk < 8; kk++) {
    short8 a[4], bw[2];
    #pragma unroll
    for (int mi = 0; mi < 4; mi++) {
      int row = mi * 16 + lr;
      int byt = (row * 512 + kk * 64 + lk * 16) ^ ((row & 7) << 4);
      a[mi] = *(const short8*)((const char*)G + byt);
    }
    #pragma unroll
    for (int ni = 0; ni < 2; ni++) {
      int col = w * 32 + ni * 16 + lr;
      bw[ni] = *(const short8*)(W2T + col * 256 + kk * 32 + lk * 8);
    }
    #pragma unroll
    for (int ni = 0; ni < 2; ni++)
      #pragma unroll
      for (int mi = 0; mi < 4; mi++)
        acc[ni][mi] = __builtin_amdgcn_mfma_f32_16x16x32_bf16(bw[ni], a[mi], acc[ni][mi], 0, 0, 0);
  }
  __syncthreads();  // all G1 reads complete before overwrite

  // ---- writeback g2 (bias+relu) bf16, b64 stores ----
  #pragma unroll
  for (int ni = 0; ni < 2; ni++) {
    int col0 = w * 32 + ni * 16 + lk * 4;
    float4 bb = *(const float4*)(b2 + col0);
    #pragma unroll
    for (int mi = 0; mi < 4; mi++) {
      int grow = mi * 16 + lr;
      float v0 = fmaxf(acc[ni][mi][0] + bb.x, 0.f);
      float v1 = fmaxf(acc[ni][mi][1] + bb.y, 0.f);
      float v2 = fmaxf(acc[ni][mi][2] + bb.z, 0.f);
      float v3 = fmaxf(acc[ni][mi][3] + bb.w, 0.f);
      uint2 pk;
      pk.x = cvtpk(v0, v1);
      pk.y = cvtpk(v2, v3);
      int byt = (grow * 512 + col0 * 2) ^ ((grow & 7) << 4);
      *(uint2*)((char*)G + byt) = pk;
    }
  }
  __syncthreads();

  // ---- GEMM2: logits = g2 @ W3 (padded 16 cols); wave w does K-slice [32w, 32w+32) ---
  f32x4 acc2[4];
  #pragma unroll
  for (int mi = 0; mi < 4; mi++) acc2[mi] = zero4;
  {
    short8 bw2 = *(const short8*)(W3Tx + lr * 256 + w * 32 + lk * 8);
    #pragma unroll
    for (int mi = 0; mi < 4; mi++) {
      int row = mi * 16 + lr;
      int kbyte = (w * 32 + lk * 8) * 2;
      int byt = (row * 512 + kbyte) ^ ((row & 7) << 4);
      short8 a = *(const short8*)((const char*)G + byt);
      acc2[mi] = __builtin_amdgcn_mfma_f32_16x16x32_bf16(a, bw2, acc2[mi], 0, 0, 0);
    }
  }
  __syncthreads();  // G reads done; alias first 8KB of G as float partials
  float* pf = (float*)G;
  if (lr < 4) {
    #pragma unroll
    for (int mi = 0; mi < 4; mi++)
      #pragma unroll
      for (int rg = 0; rg < 4; rg++) {
        int row = mi * 16 + lk * 4 + rg;
        pf[(w * 64 + row) * 4 + lr] = acc2[mi][rg];
      }
  }
  __syncthreads();

  // ---- softmax: 256 threads, one (row,col) each; sum 8 wave partials ----
  if (t < 256) {
    int r = t >> 2, c = t & 3;
    float lv = b3[c];
    #pragma unroll
    for (int wq = 0; wq < 8; wq++) lv += pf[(wq * 64 + r) * 4 + c];
    float m = fmaxf(lv, __shfl_xor(lv, 1));
    m = fmaxf(m, __shfl_xor(m, 2));
    float e = expf(lv - m);
    float s = e + __shfl_xor(e, 1);
    s += __shfl_xor(s, 2);
    bp_out[((b * 64 + i) * 64 + r) * 4 + c] = e / s;
  }
}

extern "C" void kernel_launch(void* const* d_in, const int* in_sizes, int n_in,
                              void* d_out, int out_size, void* d_ws, size_t ws_size,
                              hipStream_t stream) {
  const float* x    = (const float*)d_in[0];
  const float* adj  = (const float*)d_in[1];
  const float* cnd  = (const float*)d_in[2];
  const float* gc1W = (const float*)d_in[3];
  const float* gc1b = (const float*)d_in[4];
  const float* gc2W = (const float*)d_in[5];
  const float* gc2b = (const float*)d_in[6];
  const float* gmuW = (const float*)d_in[7];
  const float* gmub = (const float*)d_in[8];
  const float* glvW = (const float*)d_in[9];
  const float* glvb = (const float*)d_in[10];
  const float* ceW1 = (const float*)d_in[11];
  const float* ceb1 = (const float*)d_in[12];
  const float* ceW2 = (const float*)d_in[13];
  const float* ceb2 = (const float*)d_in[14];
  const float* dW1  = (const float*)d_in[15];
  const float* db1  = (const float*)d_in[16];
  const float* dW2  = (const float*)d_in[17];
  const float* db2  = (const float*)d_in[18];
  const float* dW3  = (const float*)d_in[19];
  const float* db3  = (const float*)d_in[20];
  // d_in[21..24] (at_*) are dead: mean(softmax) == 1/8 exactly
  const float* bpW1 = (const float*)d_in[25];
  const float* bpb1 = (const float*)d_in[26];
  const float* bpW2 = (const float*)d_in[27];
  const float* bpb2 = (const float*)d_in[28];
  const float* bpW3 = (const float*)d_in[29];
  const float* bpb3 = (const float*)d_in[30];
  const float* reW1 = (const float*)d_in[31];
  const float* reb1 = (const float*)d_in[32];
  const float* reW2 = (const float*)d_in[33];
  const float* reb2 = (const float*)d_in[34];

  float* out = (float*)d_out;
  float* af_out  = out;            // [64,64,64]
  float* bp_out  = out + 262144;   // [64,64,64,4]
  float* val_out = out + 1310720;  // [64,64,4]
  float* mu_out  = out + 1327104;  // [64,64,64]
  float* lv_out  = out + 1589248;  // [64,64,64]

  float* ws   = (float*)d_ws;
  float* ctf  = ws;                 // 16384
  float* ctv  = ws + 16384;         // 16384
  float* buf1 = ws + 32768;         // 1048576
  float* buf2 = buf1 + 1048576;     // 1048576  (also ax; later P)
  float* buf3 = buf2 + 1048576;     // 1048576  (later Q)
  u16*   WB   = (u16*)(buf3 + 1048576);  // 221184 u16

  k_prep<<<118, 256, 0, stream>>>(cnd, ceW1, ceb1, ceW2, ceb2, bpW1, bpb1, dW1, db1,
                                  dW2, dW3, reW1, reW2, bpW2, bpW3, ctf, ctv, WB);
  k_adjmm<64><<<dim3(1, 64), 512, 0, stream>>>(adj, x, buf2);              // ax
  k_lin256<64, 1><<<256, 512, 0, stream>>>(buf2, gc1W, gc1b, buf1);        // h1
  k_adjmm<256><<<dim3(4, 64), 512, 0, stream>>>(adj, buf1, buf2);          // ah1
  k_lin256<256, 1><<<256, 512, 0, stream>>>(buf2, gc2W, gc2b, buf3);       // h2
  k_adjmm<256><<<dim3(4, 64), 512, 0, stream>>>(adj, buf3, buf1);          // ah2
  k_mulv<<<256, 512, 0, stream>>>(buf1, gmuW, gmub, glvW, glvb, mu_out, lv_out);
  k_chain2<<<64, 1024, 0, stream>>>(WB, mu_out, ctv, ctf, db2, db3, reb1, reb2,
                                    af_out, val_out, buf2, buf3);          // P=buf2 Q=buf3
  k_bond<<<4096, 512, 0, stream>>>(buf2, buf3, WB + OW2T, bpb2, WB + OW3TX, bpb3, bp_out);
}

// Round 8
// 188.641 us; speedup vs baseline: 1.6179x; 1.1794x over previous
//
#include <hip/hip_runtime.h>

typedef short short8 __attribute__((ext_vector_type(8)));
typedef float f32x4 __attribute__((ext_vector_type(4)));
typedef unsigned short u16;
typedef unsigned int u32;

__device__ __forceinline__ u16 f2bf(float f) {
  union { float f; u32 u; } x; x.f = f;
  u32 u = x.u;
  u32 r = (u + 0x7FFFu + ((u >> 16) & 1u)) >> 16;
  return (u16)r;
}

__device__ __forceinline__ u32 cvtpk(float lo, float hi) {
  u32 r;
  asm("v_cvt_pk_bf16_f32 %0, %1, %2" : "=v"(r) : "v"(lo), "v"(hi));
  return r;
}

// ---- WB bf16-region offsets (u16 units) — decoder + bond weights only ----
#define OW2T   0        // bond W2^T      [256][256]
#define OW3TX  65536    // bond W3 padT   [16][256]
#define ODW1A  69632    // dW1[0:64]^T    [256][64]
#define ODW2   86016    // dW2^T          [256][256]
#define ODW3   151552   // dW3^T          [64][256]
#define OBPA   167936   // bpW1[0:64]^T   [256][64]  x0.125
#define OBPB   184320   // bpW1[64:128]^T [256][64]  x0.125
#define OREW1  200704   // reW1^T         [256][64]
#define OREW2  217088   // reW2 padT      [16][256]
// total 221184 u16

// =============== k_prep: ctf/ctv (blocks 0..63) + weight transposes (64..117) =========
__global__ void k_prep(const float* __restrict__ cnd, const float* __restrict__ ceW1,
                       const float* __restrict__ ceb1, const float* __restrict__ ceW2,
                       const float* __restrict__ ceb2, const float* __restrict__ bpW1,
                       const float* __restrict__ bpb1, const float* __restrict__ dW1,
                       const float* __restrict__ db1, const float* __restrict__ dW2,
                       const float* __restrict__ dW3, const float* __restrict__ reW1,
                       const float* __restrict__ reW2, const float* __restrict__ bpW2,
                       const float* __restrict__ bpW3, float* __restrict__ ctf,
                       float* __restrict__ ctvf, u16* __restrict__ WB) {
  __shared__ float h[256], c2[256];
  int bid = blockIdx.x, t = threadIdx.x;
  if (bid < 64) {
    int b = bid;
    float c0 = cnd[b * 2 + 0], c1 = cnd[b * 2 + 1];
    h[t] = fmaxf(c0 * ceW1[t] + c1 * ceW1[256 + t] + ceb1[t], 0.f);
    __syncthreads();
    float acc = ceb2[t];
    #pragma unroll 4
    for (int k = 0; k < 256; k++) acc += h[k] * ceW2[k * 256 + t];
    c2[t] = acc;
    __syncthreads();
    float a2 = bpb1[t];
    #pragma unroll 4
    for (int k = 0; k < 256; k++) a2 += c2[k] * bpW1[(128 + k) * 256 + t];
    ctf[b * 256 + t] = a2;
    float a3 = db1[t];
    #pragma unroll 4
    for (int k = 0; k < 256; k++) a3 += c2[k] * dW1[(64 + k) * 256 + t];
    ctvf[b * 256 + t] = a3;
    return;
  }
  int mb = bid - 64;  // 0..53
  const float* src; u16* dst; int C, S, Rv, eb; float sc = 1.f;
  if (mb < 4)       { src = dW1;          dst = WB + ODW1A; C = 64;  S = 256; Rv = 256; eb = mb; }
  else if (mb < 20) { src = dW2;          dst = WB + ODW2;  C = 256; S = 256; Rv = 256; eb = mb - 4; }
  else if (mb < 24) { src = dW3;          dst = WB + ODW3;  C = 256; S = 64;  Rv = 64;  eb = mb - 20; }
  else if (mb < 28) { src = bpW1;         dst = WB + OBPA;  C = 64;  S = 256; Rv = 256; eb = mb - 24; sc = 0.125f; }
  else if (mb < 32) { src = bpW1 + 16384; dst = WB + OBPB;  C = 64;  S = 256; Rv = 256; eb = mb - 28; sc = 0.125f; }
  else if (mb < 36) { src = reW1;         dst = WB + OREW1; C = 64;  S = 256; Rv = 256; eb = mb - 32; }
  else if (mb == 36){ src = reW2;         dst = WB + OREW2; C = 256; S = 4;   Rv = 4;   eb = 0; }
  else if (mb < 53) { src = bpW2;         dst = WB + OW2T;  C = 256; S = 256; Rv = 256; eb = mb - 37; }
  else              { src = bpW3;         dst = WB + OW3TX; C = 256; S = 4;   Rv = 4;   eb = 0; }
  #pragma unroll 4
  for (int it = 0; it < 16; it++) {
    int e = eb * 4096 + it * 256 + t;
    int r = e / C, c = e - r * C;
    float v = (r < Rv) ? src[c * S + r] * sc : 0.f;
    dst[e] = f2bf(v);
  }
}

// ---------------- per-batch adj @ in  (in/out: [B,64,K]); 512 threads (PROVEN r4) -----
template <int K>
__global__ void k_adjmm(const float* __restrict__ adj, const float* __restrict__ in,
                        float* __restrict__ out) {
  __shared__ float adj_s[64 * 64];
  __shared__ float in_s[64 * 64];
  int b = blockIdx.y, ch = blockIdx.x, t = threadIdx.x;
  const float* A = adj + b * 4096;
  for (int e = t; e < 4096; e += 512) adj_s[e] = A[e];
  const float* I = in + b * 64 * K + ch * 64;
  for (int e = t; e < 4096; e += 512) { int j = e >> 6, c = e & 63; in_s[e] = I[j * K + c]; }
  __syncthreads();
  int c = t & 63, ig = t >> 6;
  float acc[8];
  #pragma unroll
  for (int m = 0; m < 8; m++) acc[m] = 0.f;
  for (int j = 0; j < 64; j++) {
    float v = in_s[j * 64 + c];
    #pragma unroll
    for (int m = 0; m < 8; m++) acc[m] += adj_s[(ig + m * 8) * 64 + j] * v;
  }
  float* O = out + b * 64 * K + ch * 64;
  #pragma unroll
  for (int m = 0; m < 8; m++) O[(ig + m * 8) * K + c] = acc[m];
}

// ---------------- rows x [K,256] linear (+relu); 512 threads (PROVEN r4) --------------
template <int K, int MODE>
__global__ void k_lin256(const float* __restrict__ in, const float* __restrict__ W,
                         const float* __restrict__ bias, float* __restrict__ out) {
  __shared__ float in_s[16 * K];
  __shared__ float part[16 * 256];
  int t = threadIdx.x, r0 = blockIdx.x * 16;
  for (int e = t; e < 16 * K; e += 512) { int r = e / K, k = e % K; in_s[e] = in[(r0 + r) * K + k]; }
  __syncthreads();
  int col = t & 255, g = t >> 8;
  constexpr int KH = K / 2;
  float acc[16];
  #pragma unroll
  for (int r = 0; r < 16; r++) acc[r] = 0.f;
  #pragma unroll 4
  for (int k = g * KH; k < g * KH + KH; k++) {
    float w = W[k * 256 + col];
    #pragma unroll
    for (int r = 0; r < 16; r++) acc[r] += in_s[r * K + k] * w;
  }
  if (g == 1) {
    #pragma unroll
    for (int r = 0; r < 16; r++) part[r * 256 + col] = acc[r];
  }
  __syncthreads();
  if (g == 0) {
    float bv = bias[col];
    #pragma unroll
    for (int r = 0; r < 16; r++) {
      float v = acc[r] + part[r * 256 + col] + bv;
      if (MODE == 1) v = fmaxf(v, 0.f);
      out[(r0 + r) * 256 + col] = v;
    }
  }
}

// ---------------- mu / logvar heads; 512 threads (PROVEN r4) --------------------------
__global__ void k_mulv(const float* __restrict__ in, const float* __restrict__ Wmu,
                       const float* __restrict__ bmu, const float* __restrict__ Wlv,
                       const float* __restrict__ blv, float* __restrict__ mu_out,
                       float* __restrict__ lv_out) {
  __shared__ float in_s[16 * 256];
  __shared__ float part[8 * 16 * 64];
  int t = threadIdx.x, r0 = blockIdx.x * 16;
  for (int e = t; e < 4096; e += 512) in_s[e] = in[r0 * 256 + e];
  __syncthreads();
  int c = t & 63, g = t >> 6;
  int sel = g >> 2, kq = g & 3;
  const float* W = sel ? Wlv : Wmu;
  float acc[16];
  #pragma unroll
  for (int r = 0; r < 16; r++) acc[r] = 0.f;
  #pragma unroll 4
  for (int k = kq * 64; k < kq * 64 + 64; k++) {
    float w = W[k * 64 + c];
    #pragma unroll
    for (int r = 0; r < 16; r++) acc[r] += in_s[r * 256 + k] * w;
  }
  #pragma unroll
  for (int r = 0; r < 16; r++) part[(g * 16 + r) * 64 + c] = acc[r];
  __syncthreads();
  if (t < 128) {
    int cc = t & 63, s2 = t >> 6;
    const float* bb = s2 ? blv : bmu;
    float* O = s2 ? lv_out : mu_out;
    float bv = bb[cc];
    #pragma unroll
    for (int r = 0; r < 16; r++) {
      float v = bv;
      #pragma unroll
      for (int q = 0; q < 4; q++) v += part[((s2 * 4 + q) * 16 + r) * 64 + cc];
      O[(r0 + r) * 64 + cc] = v;
    }
  }
}

// =============== NT GEMM core: C[a][b] = sum_k V[a][k]*U[b][k] ========================
template <int KK, int WU, int WV, bool UG, bool VG, int ULEN, int VLEN>
__device__ __forceinline__ void mmrun(const u16* __restrict__ Up, int Uoff,
                                      const u16* __restrict__ Vp, int Voff,
                                      const char* lds, int ut0, int vt0, int lr, int lk,
                                      f32x4 (&acc)[WU][WV]) {
  #pragma unroll
  for (int kk = 0; kk < KK; kk++) {
    short8 uf[WU], vf[WV];
    #pragma unroll
    for (int i = 0; i < WU; i++) {
      int row = (ut0 + i) * 16 + lr;
      if constexpr (UG) {
        uf[i] = *(const short8*)(Up + row * ULEN + kk * 32 + lk * 8);
      } else {
        int byt = Uoff + row * (ULEN * 2) + kk * 64 + lk * 16;
        byt ^= (row & 7) << 4;
        uf[i] = *(const short8*)(lds + byt);
      }
    }
    #pragma unroll
    for (int j = 0; j < WV; j++) {
      int row = (vt0 + j) * 16 + lr;
      if constexpr (VG) {
        vf[j] = *(const short8*)(Vp + row * VLEN + kk * 32 + lk * 8);
      } else {
        int byt = Voff + row * (VLEN * 2) + kk * 64 + lk * 16;
        byt ^= (row & 7) << 4;
        vf[j] = *(const short8*)(lds + byt);
      }
    }
    #pragma unroll
    for (int i = 0; i < WU; i++)
      #pragma unroll
      for (int j = 0; j < WV; j++)
        acc[i][j] = __builtin_amdgcn_mfma_f32_16x16x32_bf16(uf[i], vf[j], acc[i][j], 0, 0, 0);
  }
}

__device__ __forceinline__ void st64(char* lds, int off, int rowlen, int crow, int ccol0,
                                     float a0, float a1, float a2, float a3) {
  uint2 pk; pk.x = cvtpk(a0, a1); pk.y = cvtpk(a2, a3);
  int byt = off + crow * (rowlen * 2) + ccol0 * 2;
  byt ^= (crow & 7) << 4;
  *(uint2*)(lds + byt) = pk;
}

template <int WU, int WV>
__device__ __forceinline__ void zacc(f32x4 (&acc)[WU][WV]) {
  #pragma unroll
  for (int i = 0; i < WU; i++)
    #pragma unroll
    for (int j = 0; j < WV; j++) acc[i][j] = (f32x4){0.f, 0.f, 0.f, 0.f};
}

// =============== k_chain2: decoder (mu -> f1 -> f2 -> feat -> P/Q/rh/val), bf16 =======
__global__ void __launch_bounds__(1024) k_chain2(
    const u16* __restrict__ WB, const float* __restrict__ mu_g,
    const float* __restrict__ ctv, const float* __restrict__ ctf,
    const float* __restrict__ db2, const float* __restrict__ db3,
    const float* __restrict__ reb1, const float* __restrict__ reb2,
    float* __restrict__ af_out, float* __restrict__ val_out,
    float* __restrict__ P, float* __restrict__ Q) {
  __shared__ char L[65536];
  constexpr int S2 = 0, S3 = 32768;
  int b = blockIdx.x, t = threadIdx.x;
  int w = t >> 6, lane = t & 63, lr = lane & 15, lk = lane >> 4;

  // ---- stage mu (global fp32) -> S3 bf16 [64i][64L] swizzled ----
  {
    int r = t >> 4, c0 = (t & 15) * 4;
    float4 v = *(const float4*)(mu_g + ((b * 64 + r) * 64 + c0));
    st64(L, S3, 64, r, c0, v.x, v.y, v.z, v.w);
  }
  __syncthreads();
  // ---- f1 = relu(mu@dW1a + ctv) -> S2 [64i][256n] ----
  {
    f32x4 a[2][2]; zacc(a);
    int ut0 = (w & 7) * 2, vt0 = (w >> 3) * 2;
    mmrun<2, 2, 2, true, false, 64, 64>(WB + ODW1A, 0, WB, S3, L, ut0, vt0, lr, lk, a);
    #pragma unroll
    for (int j = 0; j < 2; j++) {
      int crow = (vt0 + j) * 16 + lr;
      #pragma unroll
      for (int i = 0; i < 2; i++) {
        int cc = (ut0 + i) * 16 + lk * 4;
        float4 cv = *(const float4*)(ctv + b * 256 + cc);
        st64(L, S2, 256, crow, cc, fmaxf(a[i][j][0] + cv.x, 0.f), fmaxf(a[i][j][1] + cv.y, 0.f),
             fmaxf(a[i][j][2] + cv.z, 0.f), fmaxf(a[i][j][3] + cv.w, 0.f));
      }
    }
  }
  __syncthreads();
  // ---- f2 = relu(f1@dW2 + db2) -> S3 [64i][256n] ----
  {
    f32x4 a[2][2]; zacc(a);
    int ut0 = (w & 7) * 2, vt0 = (w >> 3) * 2;
    mmrun<8, 2, 2, true, false, 256, 256>(WB + ODW2, 0, WB, S2, L, ut0, vt0, lr, lk, a);
    #pragma unroll
    for (int j = 0; j < 2; j++) {
      int crow = (vt0 + j) * 16 + lr;
      #pragma unroll
      for (int i = 0; i < 2; i++) {
        int cc = (ut0 + i) * 16 + lk * 4;
        float4 bv = *(const float4*)(db2 + cc);
        st64(L, S3, 256, crow, cc, fmaxf(a[i][j][0] + bv.x, 0.f), fmaxf(a[i][j][1] + bv.y, 0.f),
             fmaxf(a[i][j][2] + bv.z, 0.f), fmaxf(a[i][j][3] + bv.w, 0.f));
      }
    }
  }
  __syncthreads();
  // ---- feat = sigmoid(f2@dW3 + db3) -> S2 bf16 [64i][64d]; af_out = feat*0.125 ----
  {
    f32x4 a[1][1]; zacc(a);
    int ut = w & 3, vt = w >> 2;
    mmrun<8, 1, 1, true, false, 256, 256>(WB + ODW3, 0, WB, S3, L, ut, vt, lr, lk, a);
    int crow = vt * 16 + lr, cc = ut * 16 + lk * 4;
    float4 bv = *(const float4*)(db3 + cc);
    float s0 = 1.f / (1.f + expf(-(a[0][0][0] + bv.x)));
    float s1 = 1.f / (1.f + expf(-(a[0][0][1] + bv.y)));
    float s2 = 1.f / (1.f + expf(-(a[0][0][2] + bv.z)));
    float s3 = 1.f / (1.f + expf(-(a[0][0][3] + bv.w)));
    *(float4*)(af_out + ((b * 64 + crow) * 64 + cc)) =
        make_float4(s0 * 0.125f, s1 * 0.125f, s2 * 0.125f, s3 * 0.125f);
    st64(L, S2, 64, crow, cc, s0, s1, s2, s3);
  }
  __syncthreads();
  // ---- P = 0.125*feat@bpW1a + ct ; Q = 0.125*feat@bpW1b  -> global fp32 ----
  {
    f32x4 a[2][4]; zacc(a);
    int ut0 = (w & 7) * 2;
    int sel = w >> 3;
    const u16* Up = WB + (sel ? OBPB : OBPA);
    mmrun<2, 2, 4, true, false, 64, 64>(Up, 0, WB, S2, L, ut0, 0, lr, lk, a);
    float* out = sel ? Q : P;
    #pragma unroll
    for (int i = 0; i < 2; i++) {
      int cc = (ut0 + i) * 16 + lk * 4;
      float4 cv = make_float4(0.f, 0.f, 0.f, 0.f);
      if (sel == 0) cv = *(const float4*)(ctf + b * 256 + cc);
      #pragma unroll
      for (int j = 0; j < 4; j++) {
        int crow = j * 16 + lr;
        *(float4*)(out + ((b * 64 + crow) * 256 + cc)) =
            make_float4(a[i][j][0] + cv.x, a[i][j][1] + cv.y, a[i][j][2] + cv.z, a[i][j][3] + cv.w);
      }
    }
  }
  // ---- rh = relu(feat@reW1 + reb1) -> S3 [64i][256n] ----
  {
    f32x4 a[2][2]; zacc(a);
    int ut0 = (w & 7) * 2, vt0 = (w >> 3) * 2;
    mmrun<2, 2, 2, true, false, 64, 64>(WB + OREW1, 0, WB, S2, L, ut0, vt0, lr, lk, a);
    #pragma unroll
    for (int j = 0; j < 2; j++) {
      int crow = (vt0 + j) * 16 + lr;
      #pragma unroll
      for (int i = 0; i < 2; i++) {
        int cc = (ut0 + i) * 16 + lk * 4;
        float4 bv = *(const float4*)(reb1 + cc);
        st64(L, S3, 256, crow, cc, fmaxf(a[i][j][0] + bv.x, 0.f), fmaxf(a[i][j][1] + bv.y, 0.f),
             fmaxf(a[i][j][2] + bv.z, 0.f), fmaxf(a[i][j][3] + bv.w, 0.f));
      }
    }
  }
  __syncthreads();
  // ---- val = 4*sigmoid(rh@reW2 + reb2) -> global fp32 ----
  if (w < 4) {
    f32x4 a[1][1]; zacc(a);
    mmrun<8, 1, 1, true, false, 256, 256>(WB + OREW2, 0, WB, S3, L, 0, w, lr, lk, a);
    if (lk == 0) {
      float4 rb = *(const float4*)reb2;
      float v0 = 4.f / (1.f + expf(-(a[0][0][0] + rb.x)));
      float v1 = 4.f / (1.f + expf(-(a[0][0][1] + rb.y)));
      float v2 = 4.f / (1.f + expf(-(a[0][0][2] + rb.z)));
      float v3 = 4.f / (1.f + expf(-(a[0][0][3] + rb.w)));
      *(float4*)(val_out + (b * 64 + w * 16 + lr) * 4) = make_float4(v0, v1, v2, v3);
    }
  }
}

// =============== fused bond MLP v5: 2 i-tiles/block, bw prefetch, setprio =============
__global__ void __launch_bounds__(512, 4) k_bond(
    const float* __restrict__ P, const float* __restrict__ Q,
    const u16* __restrict__ W2T, const float* __restrict__ b2,
    const u16* __restrict__ W3Tx, const float* __restrict__ b3,
    float* __restrict__ bp_out) {
  __shared__ u16 G[2 * 64 * 256];  // 64 KB: two XOR-swizzled 64x256 bf16 tiles
  // XCD-aware decode (bijective, 2048 blocks): same-b blocks share an XCD L2
  int flat = blockIdx.x;
  int xcd = flat & 7, rest = flat >> 3;  // rest 0..255
  int b = xcd * 8 + (rest >> 5);
  int i0 = (rest & 31) * 2;
  int t = threadIdx.x;
  int lane = t & 63, w = t >> 6;  // w 0..7
  int lr = lane & 15, lk = lane >> 4;

  // ---- build G[tile][j][k] = relu(P'[b,i0+tile,k] + Q[b,j,k]); Q loaded once ----
  {
    int colg = t & 63, rq = t >> 6;
    const float* Pb = P + (b * 64 + i0) * 256 + colg * 4;
    float4 p0 = *(const float4*)(Pb);
    float4 p1 = *(const float4*)(Pb + 256);
    const float* Qb = Q + b * 64 * 256;
    #pragma unroll
    for (int r = rq * 8; r < rq * 8 + 8; r++) {
      float4 q4 = *(const float4*)(Qb + r * 256 + colg * 4);
      int byt = (r * 512 + colg * 8) ^ ((r & 7) << 4);
      uint2 pk0, pk1;
      pk0.x = cvtpk(fmaxf(p0.x + q4.x, 0.f), fmaxf(p0.y + q4.y, 0.f));
      pk0.y = cvtpk(fmaxf(p0.z + q4.z, 0.f), fmaxf(p0.w + q4.w, 0.f));
      pk1.x = cvtpk(fmaxf(p1.x + q4.x, 0.f), fmaxf(p1.y + q4.y, 0.f));
      pk1.y = cvtpk(fmaxf(p1.z + q4.z, 0.f), fmaxf(p1.w + q4.w, 0.f));
      *(uint2*)((char*)G + byt) = pk0;
      *(uint2*)((char*)G + 32768 + byt) = pk1;
    }
  }
  __syncthreads();

  // ---- GEMM1 (swapped): wave owns 32 out-cols x 2 tiles; bw prefetched 1 kk ahead ----
  f32x4 acc[2][2][4];  // [tile][ni][mi]
  #pragma unroll
  for (int tl = 0; tl < 2; tl++)
    #pragma unroll
    for (int ni = 0; ni < 2; ni++)
      #pragma unroll
      for (int mi = 0; mi < 4; mi++) acc[tl][ni][mi] = (f32x4){0.f, 0.f, 0.f, 0.f};

  const u16* Wl = W2T + (w * 32 + lr) * 256 + lk * 8;
  short8 bwc0 = *(const short8*)(Wl);
  short8 bwc1 = *(const short8*)(Wl + 16 * 256);
  for (int kk = 0; kk < 8; kk++) {
    int kn = (kk + 1) & 7;
    short8 bwn0 = *(const short8*)(Wl + kn * 32);
    short8 bwn1 = *(const short8*)(Wl + 16 * 256 + kn * 32);
    __builtin_amdgcn_s_setprio(1);
    #pragma unroll
    for (int mi = 0; mi < 4; mi++) {
      int row = mi * 16 + lr;
      int byt = (row * 512 + kk * 64 + lk * 16) ^ ((row & 7) << 4);
      short8 a0 = *(const short8*)((const char*)G + byt);
      short8 a1 = *(const short8*)((const char*)G + 32768 + byt);
      acc[0][0][mi] = __builtin_amdgcn_mfma_f32_16x16x32_bf16(bwc0, a0, acc[0][0][mi], 0, 0, 0);
      acc[1][0][mi] = __builtin_amdgcn_mfma_f32_16x16x32_bf16(bwc0, a1, acc[1][0][mi], 0, 0, 0);
      acc[0][1][mi] = __builtin_amdgcn_mfma_f32_16x16x32_bf16(bwc1, a0, acc[0][1][mi], 0, 0, 0);
      acc[1][1][mi] = __builtin_amdgcn_mfma_f32_16x16x32_bf16(bwc1, a1, acc[1][1][mi], 0, 0, 0);
    }
    __builtin_amdgcn_s_setprio(0);
    bwc0 = bwn0;
    bwc1 = bwn1;
  }
  __syncthreads();  // all G1 reads complete before overwrite

  // ---- writeback g2 (bias+relu) bf16, b64 stores, both tiles ----
  #pragma unroll
  for (int tl = 0; tl < 2; tl++)
    #pragma unroll
    for (int ni = 0; ni < 2; ni++) {
      int col0 = w * 32 + ni * 16 + lk * 4;
      float4 bb = *(const float4*)(b2 + col0);
      #pragma unroll
      for (int mi = 0; mi < 4; mi++) {
        int grow = mi * 16 + lr;
        uint2 pk;
        pk.x = cvtpk(fmaxf(acc[tl][ni][mi][0] + bb.x, 0.f), fmaxf(acc[tl][ni][mi][1] + bb.y, 0.f));
        pk.y = cvtpk(fmaxf(acc[tl][ni][mi][2] + bb.z, 0.f), fmaxf(acc[tl][ni][mi][3] + bb.w, 0.f));
        int byt = ((grow * 512 + col0 * 2) ^ ((grow & 7) << 4)) + tl * 32768;
        *(uint2*)((char*)G + byt) = pk;
      }
    }
  __syncthreads();

  // ---- GEMM2: logits = g2 @ W3 (padded 16 cols); wave w K-slice [32w,32w+32), 2 tiles -
  f32x4 acc2[2][4];
  #pragma unroll
  for (int tl = 0; tl < 2; tl++)
    #pragma unroll
    for (int mi = 0; mi < 4; mi++) acc2[tl][mi] = (f32x4){0.f, 0.f, 0.f, 0.f};
  {
    short8 bw2 = *(const short8*)(W3Tx + lr * 256 + w * 32 + lk * 8);
    #pragma unroll
    for (int tl = 0; tl < 2; tl++)
      #pragma unroll
      for (int mi = 0; mi < 4; mi++) {
        int row = mi * 16 + lr;
        int byt = ((row * 512 + (w * 32 + lk * 8) * 2) ^ ((row & 7) << 4)) + tl * 32768;
        short8 a = *(const short8*)((const char*)G + byt);
        acc2[tl][mi] = __builtin_amdgcn_mfma_f32_16x16x32_bf16(a, bw2, acc2[tl][mi], 0, 0, 0);
      }
  }
  __syncthreads();  // G reads done; alias G as float partials (8KB per tile region)
  float* pf = (float*)G;
  if (lr < 4) {
    #pragma unroll
    for (int tl = 0; tl < 2; tl++)
      #pragma unroll
      for (int mi = 0; mi < 4; mi++)
        #pragma unroll
        for (int rg = 0; rg < 4; rg++) {
          int row = mi * 16 + lk * 4 + rg;
          pf[tl * 8192 + (w * 64 + row) * 4 + lr] = acc2[tl][mi][rg];
        }
  }
  __syncthreads();

  // ---- softmax: 512 threads = 2 tiles x 64 rows x 4 cols; sum 8 wave partials ----
  {
    int tl = t >> 8, idx = t & 255;
    int r = idx >> 2, c = idx & 3;
    float lv = b3[c];
    #pragma unroll
    for (int wq = 0; wq < 8; wq++) lv += pf[tl * 8192 + (wq * 64 + r) * 4 + c];
    float m = fmaxf(lv, __shfl_xor(lv, 1));
    m = fmaxf(m, __shfl_xor(m, 2));
    float e = expf(lv - m);
    float s = e + __shfl_xor(e, 1);
    s += __shfl_xor(s, 2);
    bp_out[((b * 64 + i0 + tl) * 64 + r) * 4 + c] = e / s;
  }
}

extern "C" void kernel_launch(void* const* d_in, const int* in_sizes, int n_in,
                              void* d_out, int out_size, void* d_ws, size_t ws_size,
                              hipStream_t stream) {
  const float* x    = (const float*)d_in[0];
  const float* adj  = (const float*)d_in[1];
  const float* cnd  = (const float*)d_in[2];
  const float* gc1W = (const float*)d_in[3];
  const float* gc1b = (const float*)d_in[4];
  const float* gc2W = (const float*)d_in[5];
  const float* gc2b = (const float*)d_in[6];
  const float* gmuW = (const float*)d_in[7];
  const float* gmub = (const float*)d_in[8];
  const float* glvW = (const float*)d_in[9];
  const float* glvb = (const float*)d_in[10];
  const float* ceW1 = (const float*)d_in[11];
  const float* ceb1 = (const float*)d_in[12];
  const float* ceW2 = (const float*)d_in[13];
  const float* ceb2 = (const float*)d_in[14];
  const float* dW1  = (const float*)d_in[15];
  const float* db1  = (const float*)d_in[16];
  const float* dW2  = (const float*)d_in[17];
  const float* db2  = (const float*)d_in[18];
  const float* dW3  = (const float*)d_in[19];
  const float* db3  = (const float*)d_in[20];
  // d_in[21..24] (at_*) are dead: mean(softmax) == 1/8 exactly
  const float* bpW1 = (const float*)d_in[25];
  const float* bpb1 = (const float*)d_in[26];
  const float* bpW2 = (const float*)d_in[27];
  const float* bpb2 = (const float*)d_in[28];
  const float* bpW3 = (const float*)d_in[29];
  const float* bpb3 = (const float*)d_in[30];
  const float* reW1 = (const float*)d_in[31];
  const float* reb1 = (const float*)d_in[32];
  const float* reW2 = (const float*)d_in[33];
  const float* reb2 = (const float*)d_in[34];

  float* out = (float*)d_out;
  float* af_out  = out;            // [64,64,64]
  float* bp_out  = out + 262144;   // [64,64,64,4]
  float* val_out = out + 1310720;  // [64,64,4]
  float* mu_out  = out + 1327104;  // [64,64,64]
  float* lv_out  = out + 1589248;  // [64,64,64]

  float* ws   = (float*)d_ws;
  float* ctf  = ws;                 // 16384
  float* ctv  = ws + 16384;         // 16384
  float* buf1 = ws + 32768;         // 1048576
  float* buf2 = buf1 + 1048576;     // 1048576  (also ax; later P)
  float* buf3 = buf2 + 1048576;     // 1048576  (later Q)
  u16*   WB   = (u16*)(buf3 + 1048576);  // 221184 u16

  k_prep<<<118, 256, 0, stream>>>(cnd, ceW1, ceb1, ceW2, ceb2, bpW1, bpb1, dW1, db1,
                                  dW2, dW3, reW1, reW2, bpW2, bpW3, ctf, ctv, WB);
  k_adjmm<64><<<dim3(1, 64), 512, 0, stream>>>(adj, x, buf2);              // ax
  k_lin256<64, 1><<<256, 512, 0, stream>>>(buf2, gc1W, gc1b, buf1);        // h1
  k_adjmm<256><<<dim3(4, 64), 512, 0, stream>>>(adj, buf1, buf2);          // ah1
  k_lin256<256, 1><<<256, 512, 0, stream>>>(buf2, gc2W, gc2b, buf3);       // h2
  k_adjmm<256><<<dim3(4, 64), 512, 0, stream>>>(adj, buf3, buf1);          // ah2
  k_mulv<<<256, 512, 0, stream>>>(buf1, gmuW, gmub, glvW, glvb, mu_out, lv_out);
  k_chain2<<<64, 1024, 0, stream>>>(WB, mu_out, ctv, ctf, db2, db3, reb1, reb2,
                                    af_out, val_out, buf2, buf3);          // P=buf2 Q=buf3
  k_bond<<<2048, 512, 0, stream>>>(buf2, buf3, WB + OW2T, bpb2, WB + OW3TX, bpb3, bp_out);
}

// Round 9
// 158.645 us; speedup vs baseline: 1.9239x; 1.1891x over previous
//
#include <hip/hip_runtime.h>

typedef short short8 __attribute__((ext_vector_type(8)));
typedef float f32x4 __attribute__((ext_vector_type(4)));
typedef unsigned short u16;
typedef unsigned int u32;

__device__ __forceinline__ u16 f2bf(float f) {
  union { float f; u32 u; } x; x.f = f;
  u32 u = x.u;
  u32 r = (u + 0x7FFFu + ((u >> 16) & 1u)) >> 16;
  return (u16)r;
}

__device__ __forceinline__ u32 cvtpk(float lo, float hi) {
  u32 r;
  asm("v_cvt_pk_bf16_f32 %0, %1, %2" : "=v"(r) : "v"(lo), "v"(hi));
  return r;
}

// ---- WB bf16-region offsets (u16 units) — decoder + bond weights only ----
#define OW2T   0        // bond W2^T      [256][256]
#define OW3TX  65536    // bond W3 padT   [16][256]
#define ODW1A  69632    // dW1[0:64]^T    [256][64]
#define ODW2   86016    // dW2^T          [256][256]
#define ODW3   151552   // dW3^T          [64][256]
#define OBPA   167936   // bpW1[0:64]^T   [256][64]  x0.125
#define OBPB   184320   // bpW1[64:128]^T [256][64]  x0.125
#define OREW1  200704   // reW1^T         [256][64]
#define OREW2  217088   // reW2 padT      [16][256]
// total 221184 u16

// ====== k_prep1: cond c2 (blocks 0..63) + LDS-tiled coalesced transposes (64..117) ====
__global__ void __launch_bounds__(512) k_prep1(
    const float* __restrict__ cnd, const float* __restrict__ ceW1,
    const float* __restrict__ ceb1, const float* __restrict__ ceW2,
    const float* __restrict__ ceb2, const float* __restrict__ dW1,
    const float* __restrict__ dW2, const float* __restrict__ dW3,
    const float* __restrict__ bpW1, const float* __restrict__ bpW2,
    const float* __restrict__ bpW3, const float* __restrict__ reW1,
    const float* __restrict__ reW2, float* __restrict__ c2g, u16* __restrict__ WB) {
  __shared__ float h[256], prf[256];
  __shared__ float T[64][65];
  int bid = blockIdx.x, t = threadIdx.x;
  if (bid < 64) {
    int b = bid;
    if (t < 256) {
      float c0 = cnd[b * 2 + 0], c1 = cnd[b * 2 + 1];
      h[t] = fmaxf(c0 * ceW1[t] + c1 * ceW1[256 + t] + ceb1[t], 0.f);
    }
    __syncthreads();
    int col = t & 255, g = t >> 8;
    float acc = 0.f;
    #pragma unroll 8
    for (int k = g * 128; k < g * 128 + 128; k++) acc += h[k] * ceW2[k * 256 + col];
    if (g) prf[col] = acc;
    __syncthreads();
    if (!g) c2g[b * 256 + col] = acc + prf[col] + ceb2[col];
    return;
  }
  int mb = bid - 64;  // 0..53
  if (mb >= 52) {     // reW2 / bpW3 pad-transpose (tiny)
    if (t < 256) {
      const float* s = (mb == 52) ? reW2 : bpW3;
      u16* d = WB + ((mb == 52) ? OREW2 : OW3TX);
      #pragma unroll
      for (int c = 0; c < 16; c++) {
        float v = (c < 4) ? s[t * 4 + c] : 0.f;
        d[c * 256 + t] = f2bf(v);
      }
    }
    return;
  }
  // 64x64 tile transpose: src fp32 [R][C] row-major -> dst bf16 [C][R]
  const float* src; u16* dst; int sld, dld, tr, tc; float sc = 1.f;
  if (mb < 4)       { src = dW1;           dst = WB + ODW1A; sld = 256; dld = 64;  tr = 0;            tc = mb;          }
  else if (mb < 20) { int e = mb - 4;  src = dW2;  dst = WB + ODW2; sld = 256; dld = 256; tr = e >> 2; tc = e & 3; }
  else if (mb < 24) { int e = mb - 20; src = dW3;  dst = WB + ODW3; sld = 64;  dld = 256; tr = e;      tc = 0;     }
  else if (mb < 28) { int e = mb - 24; src = bpW1; dst = WB + OBPA; sld = 256; dld = 64;  tr = 0;      tc = e; sc = 0.125f; }
  else if (mb < 32) { int e = mb - 28; src = bpW1 + 64 * 256; dst = WB + OBPB; sld = 256; dld = 64; tr = 0; tc = e; sc = 0.125f; }
  else if (mb < 36) { int e = mb - 32; src = reW1; dst = WB + OREW1; sld = 256; dld = 64; tr = 0;      tc = e;     }
  else              { int e = mb - 36; src = bpW2; dst = WB + OW2T; sld = 256; dld = 256; tr = e >> 2; tc = e & 3; }
  int rl = t >> 6, cl = t & 63;  // rl 0..7
  #pragma unroll
  for (int it = 0; it < 8; it++) {
    int r = it * 8 + rl;
    T[r][cl] = src[(tr * 64 + r) * sld + tc * 64 + cl] * sc;
  }
  __syncthreads();
  #pragma unroll
  for (int it = 0; it < 8; it++) {
    int c2_ = it * 8 + rl;
    dst[(tc * 64 + c2_) * dld + tr * 64 + cl] = f2bf(T[cl][c2_]);
  }
}

// ====== k_prep2: ctf/ctv from c2 (needs cross-block c2 -> separate launch) ============
__global__ void __launch_bounds__(512) k_prep2(
    const float* __restrict__ c2g, const float* __restrict__ bpW1,
    const float* __restrict__ bpb1, const float* __restrict__ dW1,
    const float* __restrict__ db1, float* __restrict__ ctf, float* __restrict__ ctv) {
  __shared__ float c2s[256], prf[256], prv[256];
  int b = blockIdx.x, t = threadIdx.x;
  if (t < 256) c2s[t] = c2g[b * 256 + t];
  __syncthreads();
  int col = t & 255, g = t >> 8;
  float af = 0.f, av = 0.f;
  #pragma unroll 4
  for (int k = g * 128; k < g * 128 + 128; k++) {
    float cv = c2s[k];
    af += cv * bpW1[(128 + k) * 256 + col];
    av += cv * dW1[(64 + k) * 256 + col];
  }
  if (g) { prf[col] = af; prv[col] = av; }
  __syncthreads();
  if (!g) {
    ctf[b * 256 + col] = af + prf[col] + bpb1[col];
    ctv[b * 256 + col] = av + prv[col] + db1[col];
  }
}

// ---------------- per-batch adj @ in  (in/out: [B,64,K]); 512 threads (PROVEN r4) -----
template <int K>
__global__ void k_adjmm(const float* __restrict__ adj, const float* __restrict__ in,
                        float* __restrict__ out) {
  __shared__ float adj_s[64 * 64];
  __shared__ float in_s[64 * 64];
  int b = blockIdx.y, ch = blockIdx.x, t = threadIdx.x;
  const float* A = adj + b * 4096;
  for (int e = t; e < 4096; e += 512) adj_s[e] = A[e];
  const float* I = in + b * 64 * K + ch * 64;
  for (int e = t; e < 4096; e += 512) { int j = e >> 6, c = e & 63; in_s[e] = I[j * K + c]; }
  __syncthreads();
  int c = t & 63, ig = t >> 6;
  float acc[8];
  #pragma unroll
  for (int m = 0; m < 8; m++) acc[m] = 0.f;
  for (int j = 0; j < 64; j++) {
    float v = in_s[j * 64 + c];
    #pragma unroll
    for (int m = 0; m < 8; m++) acc[m] += adj_s[(ig + m * 8) * 64 + j] * v;
  }
  float* O = out + b * 64 * K + ch * 64;
  #pragma unroll
  for (int m = 0; m < 8; m++) O[(ig + m * 8) * K + c] = acc[m];
}

// ---------------- rows x [K,256] linear (+relu); 512 threads (PROVEN r4) --------------
template <int K, int MODE>
__global__ void k_lin256(const float* __restrict__ in, const float* __restrict__ W,
                         const float* __restrict__ bias, float* __restrict__ out) {
  __shared__ float in_s[16 * K];
  __shared__ float part[16 * 256];
  int t = threadIdx.x, r0 = blockIdx.x * 16;
  for (int e = t; e < 16 * K; e += 512) { int r = e / K, k = e % K; in_s[e] = in[(r0 + r) * K + k]; }
  __syncthreads();
  int col = t & 255, g = t >> 8;
  constexpr int KH = K / 2;
  float acc[16];
  #pragma unroll
  for (int r = 0; r < 16; r++) acc[r] = 0.f;
  #pragma unroll 4
  for (int k = g * KH; k < g * KH + KH; k++) {
    float w = W[k * 256 + col];
    #pragma unroll
    for (int r = 0; r < 16; r++) acc[r] += in_s[r * K + k] * w;
  }
  if (g == 1) {
    #pragma unroll
    for (int r = 0; r < 16; r++) part[r * 256 + col] = acc[r];
  }
  __syncthreads();
  if (g == 0) {
    float bv = bias[col];
    #pragma unroll
    for (int r = 0; r < 16; r++) {
      float v = acc[r] + part[r * 256 + col] + bv;
      if (MODE == 1) v = fmaxf(v, 0.f);
      out[(r0 + r) * 256 + col] = v;
    }
  }
}

// ---------------- mu / logvar heads; 512 threads (PROVEN r4) --------------------------
__global__ void k_mulv(const float* __restrict__ in, const float* __restrict__ Wmu,
                       const float* __restrict__ bmu, const float* __restrict__ Wlv,
                       const float* __restrict__ blv, float* __restrict__ mu_out,
                       float* __restrict__ lv_out) {
  __shared__ float in_s[16 * 256];
  __shared__ float part[8 * 16 * 64];
  int t = threadIdx.x, r0 = blockIdx.x * 16;
  for (int e = t; e < 4096; e += 512) in_s[e] = in[r0 * 256 + e];
  __syncthreads();
  int c = t & 63, g = t >> 6;
  int sel = g >> 2, kq = g & 3;
  const float* W = sel ? Wlv : Wmu;
  float acc[16];
  #pragma unroll
  for (int r = 0; r < 16; r++) acc[r] = 0.f;
  #pragma unroll 4
  for (int k = kq * 64; k < kq * 64 + 64; k++) {
    float w = W[k * 64 + c];
    #pragma unroll
    for (int r = 0; r < 16; r++) acc[r] += in_s[r * 256 + k] * w;
  }
  #pragma unroll
  for (int r = 0; r < 16; r++) part[(g * 16 + r) * 64 + c] = acc[r];
  __syncthreads();
  if (t < 128) {
    int cc = t & 63, s2 = t >> 6;
    const float* bb = s2 ? blv : bmu;
    float* O = s2 ? lv_out : mu_out;
    float bv = bb[cc];
    #pragma unroll
    for (int r = 0; r < 16; r++) {
      float v = bv;
      #pragma unroll
      for (int q = 0; q < 4; q++) v += part[((s2 * 4 + q) * 16 + r) * 64 + cc];
      O[(r0 + r) * 64 + cc] = v;
    }
  }
}

// =============== NT GEMM core: C[a][b] = sum_k V[a][k]*U[b][k] ========================
template <int KK, int WU, int WV, bool UG, bool VG, int ULEN, int VLEN>
__device__ __forceinline__ void mmrun(const u16* __restrict__ Up, int Uoff,
                                      const u16* __restrict__ Vp, int Voff,
                                      const char* lds, int ut0, int vt0, int lr, int lk,
                                      f32x4 (&acc)[WU][WV]) {
  #pragma unroll
  for (int kk = 0; kk < KK; kk++) {
    short8 uf[WU], vf[WV];
    #pragma unroll
    for (int i = 0; i < WU; i++) {
      int row = (ut0 + i) * 16 + lr;
      if constexpr (UG) {
        uf[i] = *(const short8*)(Up + row * ULEN + kk * 32 + lk * 8);
      } else {
        int byt = Uoff + row * (ULEN * 2) + kk * 64 + lk * 16;
        byt ^= (row & 7) << 4;
        uf[i] = *(const short8*)(lds + byt);
      }
    }
    #pragma unroll
    for (int j = 0; j < WV; j++) {
      int row = (vt0 + j) * 16 + lr;
      if constexpr (VG) {
        vf[j] = *(const short8*)(Vp + row * VLEN + kk * 32 + lk * 8);
      } else {
        int byt = Voff + row * (VLEN * 2) + kk * 64 + lk * 16;
        byt ^= (row & 7) << 4;
        vf[j] = *(const short8*)(lds + byt);
      }
    }
    #pragma unroll
    for (int i = 0; i < WU; i++)
      #pragma unroll
      for (int j = 0; j < WV; j++)
        acc[i][j] = __builtin_amdgcn_mfma_f32_16x16x32_bf16(uf[i], vf[j], acc[i][j], 0, 0, 0);
  }
}

__device__ __forceinline__ void st64(char* lds, int off, int rowlen, int crow, int ccol0,
                                     float a0, float a1, float a2, float a3) {
  uint2 pk; pk.x = cvtpk(a0, a1); pk.y = cvtpk(a2, a3);
  int byt = off + crow * (rowlen * 2) + ccol0 * 2;
  byt ^= (crow & 7) << 4;
  *(uint2*)(lds + byt) = pk;
}

template <int WU, int WV>
__device__ __forceinline__ void zacc(f32x4 (&acc)[WU][WV]) {
  #pragma unroll
  for (int i = 0; i < WU; i++)
    #pragma unroll
    for (int j = 0; j < WV; j++) acc[i][j] = (f32x4){0.f, 0.f, 0.f, 0.f};
}

// =============== k_chain2: decoder (mu -> f1 -> f2 -> feat -> P/Q/rh/val), bf16 =======
__global__ void __launch_bounds__(1024) k_chain2(
    const u16* __restrict__ WB, const float* __restrict__ mu_g,
    const float* __restrict__ ctv, const float* __restrict__ ctf,
    const float* __restrict__ db2, const float* __restrict__ db3,
    const float* __restrict__ reb1, const float* __restrict__ reb2,
    float* __restrict__ af_out, float* __restrict__ val_out,
    float* __restrict__ P, float* __restrict__ Q) {
  __shared__ char L[65536];
  constexpr int S2 = 0, S3 = 32768;
  int b = blockIdx.x, t = threadIdx.x;
  int w = t >> 6, lane = t & 63, lr = lane & 15, lk = lane >> 4;

  // ---- stage mu (global fp32) -> S3 bf16 [64i][64L] swizzled ----
  {
    int r = t >> 4, c0 = (t & 15) * 4;
    float4 v = *(const float4*)(mu_g + ((b * 64 + r) * 64 + c0));
    st64(L, S3, 64, r, c0, v.x, v.y, v.z, v.w);
  }
  __syncthreads();
  // ---- f1 = relu(mu@dW1a + ctv) -> S2 [64i][256n] ----
  {
    f32x4 a[2][2]; zacc(a);
    int ut0 = (w & 7) * 2, vt0 = (w >> 3) * 2;
    mmrun<2, 2, 2, true, false, 64, 64>(WB + ODW1A, 0, WB, S3, L, ut0, vt0, lr, lk, a);
    #pragma unroll
    for (int j = 0; j < 2; j++) {
      int crow = (vt0 + j) * 16 + lr;
      #pragma unroll
      for (int i = 0; i < 2; i++) {
        int cc = (ut0 + i) * 16 + lk * 4;
        float4 cv = *(const float4*)(ctv + b * 256 + cc);
        st64(L, S2, 256, crow, cc, fmaxf(a[i][j][0] + cv.x, 0.f), fmaxf(a[i][j][1] + cv.y, 0.f),
             fmaxf(a[i][j][2] + cv.z, 0.f), fmaxf(a[i][j][3] + cv.w, 0.f));
      }
    }
  }
  __syncthreads();
  // ---- f2 = relu(f1@dW2 + db2) -> S3 [64i][256n] ----
  {
    f32x4 a[2][2]; zacc(a);
    int ut0 = (w & 7) * 2, vt0 = (w >> 3) * 2;
    mmrun<8, 2, 2, true, false, 256, 256>(WB + ODW2, 0, WB, S2, L, ut0, vt0, lr, lk, a);
    #pragma unroll
    for (int j = 0; j < 2; j++) {
      int crow = (vt0 + j) * 16 + lr;
      #pragma unroll
      for (int i = 0; i < 2; i++) {
        int cc = (ut0 + i) * 16 + lk * 4;
        float4 bv = *(const float4*)(db2 + cc);
        st64(L, S3, 256, crow, cc, fmaxf(a[i][j][0] + bv.x, 0.f), fmaxf(a[i][j][1] + bv.y, 0.f),
             fmaxf(a[i][j][2] + bv.z, 0.f), fmaxf(a[i][j][3] + bv.w, 0.f));
      }
    }
  }
  __syncthreads();
  // ---- feat = sigmoid(f2@dW3 + db3) -> S2 bf16 [64i][64d]; af_out = feat*0.125 ----
  {
    f32x4 a[1][1]; zacc(a);
    int ut = w & 3, vt = w >> 2;
    mmrun<8, 1, 1, true, false, 256, 256>(WB + ODW3, 0, WB, S3, L, ut, vt, lr, lk, a);
    int crow = vt * 16 + lr, cc = ut * 16 + lk * 4;
    float4 bv = *(const float4*)(db3 + cc);
    float s0 = 1.f / (1.f + expf(-(a[0][0][0] + bv.x)));
    float s1 = 1.f / (1.f + expf(-(a[0][0][1] + bv.y)));
    float s2 = 1.f / (1.f + expf(-(a[0][0][2] + bv.z)));
    float s3 = 1.f / (1.f + expf(-(a[0][0][3] + bv.w)));
    *(float4*)(af_out + ((b * 64 + crow) * 64 + cc)) =
        make_float4(s0 * 0.125f, s1 * 0.125f, s2 * 0.125f, s3 * 0.125f);
    st64(L, S2, 64, crow, cc, s0, s1, s2, s3);
  }
  __syncthreads();
  // ---- P = 0.125*feat@bpW1a + ct ; Q = 0.125*feat@bpW1b  -> global fp32 ----
  {
    f32x4 a[2][4]; zacc(a);
    int ut0 = (w & 7) * 2;
    int sel = w >> 3;
    const u16* Up = WB + (sel ? OBPB : OBPA);
    mmrun<2, 2, 4, true, false, 64, 64>(Up, 0, WB, S2, L, ut0, 0, lr, lk, a);
    float* out = sel ? Q : P;
    #pragma unroll
    for (int i = 0; i < 2; i++) {
      int cc = (ut0 + i) * 16 + lk * 4;
      float4 cv = make_float4(0.f, 0.f, 0.f, 0.f);
      if (sel == 0) cv = *(const float4*)(ctf + b * 256 + cc);
      #pragma unroll
      for (int j = 0; j < 4; j++) {
        int crow = j * 16 + lr;
        *(float4*)(out + ((b * 64 + crow) * 256 + cc)) =
            make_float4(a[i][j][0] + cv.x, a[i][j][1] + cv.y, a[i][j][2] + cv.z, a[i][j][3] + cv.w);
      }
    }
  }
  // ---- rh = relu(feat@reW1 + reb1) -> S3 [64i][256n] ----
  {
    f32x4 a[2][2]; zacc(a);
    int ut0 = (w & 7) * 2, vt0 = (w >> 3) * 2;
    mmrun<2, 2, 2, true, false, 64, 64>(WB + OREW1, 0, WB, S2, L, ut0, vt0, lr, lk, a);
    #pragma unroll
    for (int j = 0; j < 2; j++) {
      int crow = (vt0 + j) * 16 + lr;
      #pragma unroll
      for (int i = 0; i < 2; i++) {
        int cc = (ut0 + i) * 16 + lk * 4;
        float4 bv = *(const float4*)(reb1 + cc);
        st64(L, S3, 256, crow, cc, fmaxf(a[i][j][0] + bv.x, 0.f), fmaxf(a[i][j][1] + bv.y, 0.f),
             fmaxf(a[i][j][2] + bv.z, 0.f), fmaxf(a[i][j][3] + bv.w, 0.f));
      }
    }
  }
  __syncthreads();
  // ---- val = 4*sigmoid(rh@reW2 + reb2) -> global fp32 ----
  if (w < 4) {
    f32x4 a[1][1]; zacc(a);
    mmrun<8, 1, 1, true, false, 256, 256>(WB + OREW2, 0, WB, S3, L, 0, w, lr, lk, a);
    if (lk == 0) {
      float4 rb = *(const float4*)reb2;
      float v0 = 4.f / (1.f + expf(-(a[0][0][0] + rb.x)));
      float v1 = 4.f / (1.f + expf(-(a[0][0][1] + rb.y)));
      float v2 = 4.f / (1.f + expf(-(a[0][0][2] + rb.z)));
      float v3 = 4.f / (1.f + expf(-(a[0][0][3] + rb.w)));
      *(float4*)(val_out + (b * 64 + w * 16 + lr) * 4) = make_float4(v0, v1, v2, v3);
    }
  }
}

// =============== fused bond MLP v5 (PROVEN r8): 2 i-tiles, prefetch, setprio ==========
__global__ void __launch_bounds__(512, 4) k_bond(
    const float* __restrict__ P, const float* __restrict__ Q,
    const u16* __restrict__ W2T, const float* __restrict__ b2,
    const u16* __restrict__ W3Tx, const float* __restrict__ b3,
    float* __restrict__ bp_out) {
  __shared__ u16 G[2 * 64 * 256];  // 64 KB: two XOR-swizzled 64x256 bf16 tiles
  int flat = blockIdx.x;
  int xcd = flat & 7, rest = flat >> 3;
  int b = xcd * 8 + (rest >> 5);
  int i0 = (rest & 31) * 2;
  int t = threadIdx.x;
  int lane = t & 63, w = t >> 6;
  int lr = lane & 15, lk = lane >> 4;

  {
    int colg = t & 63, rq = t >> 6;
    const float* Pb = P + (b * 64 + i0) * 256 + colg * 4;
    float4 p0 = *(const float4*)(Pb);
    float4 p1 = *(const float4*)(Pb + 256);
    const float* Qb = Q + b * 64 * 256;
    #pragma unroll
    for (int r = rq * 8; r < rq * 8 + 8; r++) {
      float4 q4 = *(const float4*)(Qb + r * 256 + colg * 4);
      int byt = (r * 512 + colg * 8) ^ ((r & 7) << 4);
      uint2 pk0, pk1;
      pk0.x = cvtpk(fmaxf(p0.x + q4.x, 0.f), fmaxf(p0.y + q4.y, 0.f));
      pk0.y = cvtpk(fmaxf(p0.z + q4.z, 0.f), fmaxf(p0.w + q4.w, 0.f));
      pk1.x = cvtpk(fmaxf(p1.x + q4.x, 0.f), fmaxf(p1.y + q4.y, 0.f));
      pk1.y = cvtpk(fmaxf(p1.z + q4.z, 0.f), fmaxf(p1.w + q4.w, 0.f));
      *(uint2*)((char*)G + byt) = pk0;
      *(uint2*)((char*)G + 32768 + byt) = pk1;
    }
  }
  __syncthreads();

  f32x4 acc[2][2][4];
  #pragma unroll
  for (int tl = 0; tl < 2; tl++)
    #pragma unroll
    for (int ni = 0; ni < 2; ni++)
      #pragma unroll
      for (int mi = 0; mi < 4; mi++) acc[tl][ni][mi] = (f32x4){0.f, 0.f, 0.f, 0.f};

  const u16* Wl = W2T + (w * 32 + lr) * 256 + lk * 8;
  short8 bwc0 = *(const short8*)(Wl);
  short8 bwc1 = *(const short8*)(Wl + 16 * 256);
  for (int kk = 0; kk < 8; kk++) {
    int kn = (kk + 1) & 7;
    short8 bwn0 = *(const short8*)(Wl + kn * 32);
    short8 bwn1 = *(const short8*)(Wl + 16 * 256 + kn * 32);
    __builtin_amdgcn_s_setprio(1);
    #pragma unroll
    for (int mi = 0; mi < 4; mi++) {
      int row = mi * 16 + lr;
      int byt = (row * 512 + kk * 64 + lk * 16) ^ ((row & 7) << 4);
      short8 a0 = *(const short8*)((const char*)G + byt);
      short8 a1 = *(const short8*)((const char*)G + 32768 + byt);
      acc[0][0][mi] = __builtin_amdgcn_mfma_f32_16x16x32_bf16(bwc0, a0, acc[0][0][mi], 0, 0, 0);
      acc[1][0][mi] = __builtin_amdgcn_mfma_f32_16x16x32_bf16(bwc0, a1, acc[1][0][mi], 0, 0, 0);
      acc[0][1][mi] = __builtin_amdgcn_mfma_f32_16x16x32_bf16(bwc1, a0, acc[0][1][mi], 0, 0, 0);
      acc[1][1][mi] = __builtin_amdgcn_mfma_f32_16x16x32_bf16(bwc1, a1, acc[1][1][mi], 0, 0, 0);
    }
    __builtin_amdgcn_s_setprio(0);
    bwc0 = bwn0;
    bwc1 = bwn1;
  }
  __syncthreads();

  #pragma unroll
  for (int tl = 0; tl < 2; tl++)
    #pragma unroll
    for (int ni = 0; ni < 2; ni++) {
      int col0 = w * 32 + ni * 16 + lk * 4;
      float4 bb = *(const float4*)(b2 + col0);
      #pragma unroll
      for (int mi = 0; mi < 4; mi++) {
        int grow = mi * 16 + lr;
        uint2 pk;
        pk.x = cvtpk(fmaxf(acc[tl][ni][mi][0] + bb.x, 0.f), fmaxf(acc[tl][ni][mi][1] + bb.y, 0.f));
        pk.y = cvtpk(fmaxf(acc[tl][ni][mi][2] + bb.z, 0.f), fmaxf(acc[tl][ni][mi][3] + bb.w, 0.f));
        int byt = ((grow * 512 + col0 * 2) ^ ((grow & 7) << 4)) + tl * 32768;
        *(uint2*)((char*)G + byt) = pk;
      }
    }
  __syncthreads();

  f32x4 acc2[2][4];
  #pragma unroll
  for (int tl = 0; tl < 2; tl++)
    #pragma unroll
    for (int mi = 0; mi < 4; mi++) acc2[tl][mi] = (f32x4){0.f, 0.f, 0.f, 0.f};
  {
    short8 bw2 = *(const short8*)(W3Tx + lr * 256 + w * 32 + lk * 8);
    #pragma unroll
    for (int tl = 0; tl < 2; tl++)
      #pragma unroll
      for (int mi = 0; mi < 4; mi++) {
        int row = mi * 16 + lr;
        int byt = ((row * 512 + (w * 32 + lk * 8) * 2) ^ ((row & 7) << 4)) + tl * 32768;
        short8 a = *(const short8*)((const char*)G + byt);
        acc2[tl][mi] = __builtin_amdgcn_mfma_f32_16x16x32_bf16(a, bw2, acc2[tl][mi], 0, 0, 0);
      }
  }
  __syncthreads();
  float* pf = (float*)G;
  if (lr < 4) {
    #pragma unroll
    for (int tl = 0; tl < 2; tl++)
      #pragma unroll
      for (int mi = 0; mi < 4; mi++)
        #pragma unroll
        for (int rg = 0; rg < 4; rg++) {
          int row = mi * 16 + lk * 4 + rg;
          pf[tl * 8192 + (w * 64 + row) * 4 + lr] = acc2[tl][mi][rg];
        }
  }
  __syncthreads();

  {
    int tl = t >> 8, idx = t & 255;
    int r = idx >> 2, c = idx & 3;
    float lv = b3[c];
    #pragma unroll
    for (int wq = 0; wq < 8; wq++) lv += pf[tl * 8192 + (wq * 64 + r) * 4 + c];
    float m = fmaxf(lv, __shfl_xor(lv, 1));
    m = fmaxf(m, __shfl_xor(m, 2));
    float e = expf(lv - m);
    float s = e + __shfl_xor(e, 1);
    s += __shfl_xor(s, 2);
    bp_out[((b * 64 + i0 + tl) * 64 + r) * 4 + c] = e / s;
  }
}

extern "C" void kernel_launch(void* const* d_in, const int* in_sizes, int n_in,
                              void* d_out, int out_size, void* d_ws, size_t ws_size,
                              hipStream_t stream) {
  const float* x    = (const float*)d_in[0];
  const float* adj  = (const float*)d_in[1];
  const float* cnd  = (const float*)d_in[2];
  const float* gc1W = (const float*)d_in[3];
  const float* gc1b = (const float*)d_in[4];
  const float* gc2W = (const float*)d_in[5];
  const float* gc2b = (const float*)d_in[6];
  const float* gmuW = (const float*)d_in[7];
  const float* gmub = (const float*)d_in[8];
  const float* glvW = (const float*)d_in[9];
  const float* glvb = (const float*)d_in[10];
  const float* ceW1 = (const float*)d_in[11];
  const float* ceb1 = (const float*)d_in[12];
  const float* ceW2 = (const float*)d_in[13];
  const float* ceb2 = (const float*)d_in[14];
  const float* dW1  = (const float*)d_in[15];
  const float* db1  = (const float*)d_in[16];
  const float* dW2  = (const float*)d_in[17];
  const float* db2  = (const float*)d_in[18];
  const float* dW3  = (const float*)d_in[19];
  const float* db3  = (const float*)d_in[20];
  // d_in[21..24] (at_*) are dead: mean(softmax) == 1/8 exactly
  const float* bpW1 = (const float*)d_in[25];
  const float* bpb1 = (const float*)d_in[26];
  const float* bpW2 = (const float*)d_in[27];
  const float* bpb2 = (const float*)d_in[28];
  const float* bpW3 = (const float*)d_in[29];
  const float* bpb3 = (const float*)d_in[30];
  const float* reW1 = (const float*)d_in[31];
  const float* reb1 = (const float*)d_in[32];
  const float* reW2 = (const float*)d_in[33];
  const float* reb2 = (const float*)d_in[34];

  float* out = (float*)d_out;
  float* af_out  = out;            // [64,64,64]
  float* bp_out  = out + 262144;   // [64,64,64,4]
  float* val_out = out + 1310720;  // [64,64,4]
  float* mu_out  = out + 1327104;  // [64,64,64]
  float* lv_out  = out + 1589248;  // [64,64,64]

  float* ws   = (float*)d_ws;
  float* ctf  = ws;                 // 16384
  float* ctv  = ws + 16384;         // 16384
  float* c2g  = ws + 32768;         // 16384
  float* buf1 = ws + 49152;         // 1048576
  float* buf2 = buf1 + 1048576;     // 1048576  (also ax; later P)
  float* buf3 = buf2 + 1048576;     // 1048576  (later Q)
  u16*   WB   = (u16*)(buf3 + 1048576);  // 221184 u16

  k_prep1<<<118, 512, 0, stream>>>(cnd, ceW1, ceb1, ceW2, ceb2, dW1, dW2, dW3,
                                   bpW1, bpW2, bpW3, reW1, reW2, c2g, WB);
  k_prep2<<<64, 512, 0, stream>>>(c2g, bpW1, bpb1, dW1, db1, ctf, ctv);
  k_adjmm<64><<<dim3(1, 64), 512, 0, stream>>>(adj, x, buf2);              // ax
  k_lin256<64, 1><<<256, 512, 0, stream>>>(buf2, gc1W, gc1b, buf1);        // h1
  k_adjmm<256><<<dim3(4, 64), 512, 0, stream>>>(adj, buf1, buf2);          // ah1
  k_lin256<256, 1><<<256, 512, 0, stream>>>(buf2, gc2W, gc2b, buf3);       // h2
  k_adjmm<256><<<dim3(4, 64), 512, 0, stream>>>(adj, buf3, buf1);          // ah2
  k_mulv<<<256, 512, 0, stream>>>(buf1, gmuW, gmub, glvW, glvb, mu_out, lv_out);
  k_chain2<<<64, 1024, 0, stream>>>(WB, mu_out, ctv, ctf, db2, db3, reb1, reb2,
                                    af_out, val_out, buf2, buf3);          // P=buf2 Q=buf3
  k_bond<<<2048, 512, 0, stream>>>(buf2, buf3, WB + OW2T, bpb2, WB + OW3TX, bpb3, bp_out);
}